// Round 7
// baseline (787.406 us; speedup 1.0000x reference)
//
#include <hip/hip_runtime.h>
#include <cstddef>
#include <cstdint>

#define DIN 64
#define HID 128
#define NBKMAX 256   // max dst buckets of 512 nodes -> supports N <= 131072
#define EPB 8192     // edges per bin-pass block

typedef _Float16 half4v __attribute__((ext_vector_type(4)));
typedef _Float16 half8v __attribute__((ext_vector_type(8)));
typedef float f32x16 __attribute__((ext_vector_type(16)));

// ---- order-preserving float<->uint for atomicMax-based segment max ----
__device__ __forceinline__ unsigned encf(float f) {
    unsigned b = __float_as_uint(f);
    return (b & 0x80000000u) ? ~b : (b | 0x80000000u);
}
__device__ __forceinline__ float decf(unsigned u) {
    unsigned b = (u & 0x80000000u) ? (u & 0x7FFFFFFFu) : ~u;
    return __uint_as_float(b);
}

// ---- 3 matrix adds in one launch (Wroot pre-sums) ----
__global__ void matadd3_k(const float* a0, const float* b0f, float* o0, int n0,
                          const float* a1, const float* b1f, float* o1, int n1,
                          const float* a2, const float* b2f, float* o2, int n2) {
    int r = blockIdx.y;
    const float* a = r == 0 ? a0 : (r == 1 ? a1 : a2);
    const float* b = r == 0 ? b0f : (r == 1 ? b1f : b2f);
    float* o = r == 0 ? o0 : (r == 1 ? o1 : o2);
    int n = r == 0 ? n0 : (r == 1 ? n1 : n2);
    int i = blockIdx.x * 256 + threadIdx.x;
    if (i < n) o[i] = a[i] + b[i];
}

// ---- fp32 -> f16 for both inputs in one launch ----
__global__ void conv_x2_k(const float* s0, _Float16* d0, int n40,
                          const float* s1, _Float16* d1, int n41) {
    int r = blockIdx.y;
    const float* s = r == 0 ? s0 : s1;
    _Float16* d = r == 0 ? d0 : d1;
    int n4 = r == 0 ? n40 : n41;
    int i = blockIdx.x * 256 + threadIdx.x;
    if (i >= n4) return;
    float4 v = *reinterpret_cast<const float4*>(&s[i * 4]);
    half4v h;
    h.x = (_Float16)v.x; h.y = (_Float16)v.y; h.z = (_Float16)v.z; h.w = (_Float16)v.w;
    *reinterpret_cast<half4v*>(&d[i * 4]) = h;
}

// ---- 7 weight convert+transpose jobs in one launch ----
struct CW { const float* src; _Float16* dst; int K; int total; };
__global__ void conv_w7_k(CW c0, CW c1, CW c2, CW c3, CW c4, CW c5, CW c6) {
    CW J;
    switch (blockIdx.y) {
        case 0: J = c0; break; case 1: J = c1; break; case 2: J = c2; break;
        case 3: J = c3; break; case 4: J = c4; break; case 5: J = c5; break;
        default: J = c6; break;
    }
    int i = blockIdx.x * 256 + threadIdx.x;
    if (i >= J.total) return;
    int m = i / (J.K * HID);
    int rem = i % (J.K * HID);
    int k = rem / HID;
    int col = rem % HID;
    J.dst[(size_t)m * HID * J.K + (size_t)col * J.K + k] = (_Float16)J.src[i];
}

// ================= CSR build via cache-local counting sort =================
__global__ __launch_bounds__(256) void bhist_k(const int* e0, const int* e1, const int* e2, int E,
                                               int* c0, int* c1, int* c2) {
    int r = blockIdx.y;
    const int* ei = r == 0 ? e0 : (r == 1 ? e1 : e2);
    int* cnt = r == 0 ? c0 : (r == 1 ? c1 : c2);
    __shared__ int sc[NBKMAX];
    int t = threadIdx.x;
    sc[t] = 0;
    __syncthreads();
    int base = blockIdx.x * EPB;
    int n = min(EPB, E - base);
    for (int i = t; i < n; i += 256)
        atomicAdd(&sc[(unsigned)ei[E + base + i] >> 9], 1);
    __syncthreads();
    if (sc[t]) atomicAdd(&cnt[t], sc[t]);
}

__global__ __launch_bounds__(256) void bscan_k(int* c0, int* bb0, int* cu0, int* rp0, int n0,
                                               int* c1, int* bb1, int* cu1, int* rp1, int n1,
                                               int* c2, int* bb2, int* cu2, int* rp2, int n2,
                                               int E) {
    __shared__ int sh[256];
    int t = threadIdx.x;
    for (int r = 0; r < 3; ++r) {
        int* cnt = r == 0 ? c0 : (r == 1 ? c1 : c2);
        int* bb  = r == 0 ? bb0 : (r == 1 ? bb1 : bb2);
        int* cu  = r == 0 ? cu0 : (r == 1 ? cu1 : cu2);
        int* rp  = r == 0 ? rp0 : (r == 1 ? rp1 : rp2);
        int N    = r == 0 ? n0 : (r == 1 ? n1 : n2);
        int v = cnt[t];
        sh[t] = v;
        __syncthreads();
        for (int off = 1; off < 256; off <<= 1) {
            int val = (t >= off) ? sh[t - off] : 0;
            __syncthreads();
            sh[t] += val;
            __syncthreads();
        }
        int ex = sh[t] - v;
        bb[t] = ex;
        cu[t] = ex;
        if (t == 255) bb[256] = sh[255];
        if (t == 0) rp[N] = E;
        __syncthreads();
    }
}

__global__ __launch_bounds__(256) void bin_k(const int* e0, const int* e1, const int* e2, int E,
                                             int* cu0, int* cu1, int* cu2,
                                             unsigned* t0, unsigned* t1, unsigned* t2) {
    int r = blockIdx.y;
    const int* ei = r == 0 ? e0 : (r == 1 ? e1 : e2);
    int* gcur = r == 0 ? cu0 : (r == 1 ? cu1 : cu2);
    unsigned* temp = r == 0 ? t0 : (r == 1 ? t1 : t2);
    __shared__ unsigned pk[EPB];
    __shared__ unsigned short bkb[EPB];
    __shared__ int cnt[NBKMAX];
    __shared__ int scn[NBKMAX];
    __shared__ int rb[NBKMAX];
    int t = threadIdx.x;
    int base = blockIdx.x * EPB;
    int n = min(EPB, E - base);
    cnt[t] = 0;
    __syncthreads();
    for (int i = t; i < n; i += 256)
        atomicAdd(&cnt[(unsigned)ei[E + base + i] >> 9], 1);
    __syncthreads();
    {
        int v = cnt[t];
        scn[t] = v;
        __syncthreads();
        for (int off = 1; off < 256; off <<= 1) {
            int val = (t >= off) ? scn[t - off] : 0;
            __syncthreads();
            scn[t] += val;
            __syncthreads();
        }
        int ex = scn[t] - v;
        __syncthreads();
        scn[t] = ex;
    }
    {
        int c = cnt[t];
        rb[t] = c ? atomicAdd(&gcur[t], c) : 0;
        cnt[t] = 0;
    }
    __syncthreads();
    for (int i = t; i < n; i += 256) {
        int s = ei[base + i];
        int d = ei[E + base + i];
        int b = (unsigned)d >> 9;
        int slot = scn[b] + atomicAdd(&cnt[b], 1);
        pk[slot] = ((unsigned)s << 9) | (unsigned)(d & 511);
        bkb[slot] = (unsigned short)b;
    }
    __syncthreads();
    for (int i = t; i < n; i += 256) {
        int b = bkb[i];
        temp[rb[b] + (i - scn[b])] = pk[i];
    }
}

__global__ __launch_bounds__(256) void bcsr_k(const unsigned* t0, const unsigned* t1, const unsigned* t2,
                                              const int* bb0, const int* bb1, const int* bb2,
                                              int* rp0, int* rp1, int* rp2,
                                              int* a0, int* a1, int* a2,
                                              int n0, int n1, int n2) {
    int r = blockIdx.y;
    const unsigned* temp = r == 0 ? t0 : (r == 1 ? t1 : t2);
    const int* bb = r == 0 ? bb0 : (r == 1 ? bb1 : bb2);
    int* rp = r == 0 ? rp0 : (r == 1 ? rp1 : rp2);
    int* adj = r == 0 ? a0 : (r == 1 ? a1 : a2);
    int N = r == 0 ? n0 : (r == 1 ? n1 : n2);
    int b = blockIdx.x;
    int lo = bb[b], hi = bb[b + 1];
    __shared__ int cnt[512];
    __shared__ int sh[256];
    int t = threadIdx.x;
    cnt[t] = 0; cnt[t + 256] = 0;
    __syncthreads();
    for (int i = lo + t; i < hi; i += 256)
        atomicAdd(&cnt[temp[i] & 511], 1);
    __syncthreads();
    int c0 = cnt[2 * t], c1 = cnt[2 * t + 1];
    sh[t] = c0 + c1;
    __syncthreads();
    for (int off = 1; off < 256; off <<= 1) {
        int v = (t >= off) ? sh[t - off] : 0;
        __syncthreads();
        sh[t] += v;
        __syncthreads();
    }
    int pairExcl = sh[t] - (c0 + c1);
    __syncthreads();
    int e0x = lo + pairExcl;
    int e1x = e0x + c0;
    cnt[2 * t] = e0x;
    cnt[2 * t + 1] = e1x;
    int nodeBase = b * 512;
    if (nodeBase + 2 * t < N) rp[nodeBase + 2 * t] = e0x;
    if (nodeBase + 2 * t + 1 < N) rp[nodeBase + 2 * t + 1] = e1x;
    __syncthreads();
    for (int i = lo + t; i < hi; i += 256) {
        unsigned p = temp[i];
        int pos = atomicAdd(&cnt[p & 511], 1);
        adj[pos] = p >> 9;
    }
}

// ======================= fused gather + MFMA GEMM =======================
// O[N,128] = sum_s Agg_s(X_s)[N,K] @ W_s[K,128] + b0 (+ b1), opt ReLU.
// Agg_s = CSR gather-sum (rp != null) or identity/root (rp == null).
// Per source: 256 threads gather rows straight into frag-layout LDS (f32 acc
// in regs -> f16 -> 16 B store), barrier, MFMA sweep over K (weights from L2).
// No AGG intermediate in global memory. Two jobs (pe+router) per launch.
struct FJob {
    const _Float16* X0; const int* rp0; const int* adj0; const _Float16* W0;
    const _Float16* X1; const int* rp1; const int* adj1; const _Float16* W1;
    const _Float16* X2; const int* rp2; const int* adj2; const _Float16* W2;
    const float* b0; const float* b1;
    _Float16* O;
    int N; int nsrc; int gb;
};

template <int K, bool RELU>
__global__ __launch_bounds__(256) void fgemm_k(FJob j0, FJob j1) {
    constexpr int KS = K / 16;        // MFMA k-steps per source
    constexpr int TPN = K / 8;        // gather threads per node
    constexpr int NPB = 256 / TPN;    // nodes per gather pass
    __shared__ _Float16 Alds[128 * K];  // frag-layout A tile (16/32 KB)

    const bool second = ((int)blockIdx.x >= j0.gb);
    const FJob J = second ? j1 : j0;
    const int bx = blockIdx.x - (second ? j0.gb : 0);
    const int tid = threadIdx.x;
    const int lane = tid & 63;
    const int w = tid >> 6;
    const int wr = w & 1, wc = w >> 1;
    const int rowBase = bx * 128;

    f32x16 acc[2][2];
#pragma unroll
    for (int r = 0; r < 2; ++r)
#pragma unroll
        for (int c = 0; c < 2; ++c)
#pragma unroll
            for (int q = 0; q < 16; ++q) acc[r][c][q] = 0.0f;

    const int nloc = tid / TPN;
    const int glane = tid % TPN;
    const int gt = glane >> 1;    // k16 step of this 8-feature chunk
    const int gk8 = glane & 1;    // which 8-half within the 16

    for (int s = 0; s < J.nsrc; ++s) {
        const _Float16* X; const int* rp; const int* adj; const _Float16* Wt;
        if (s == 0) { X = J.X0; rp = J.rp0; adj = J.adj0; Wt = J.W0; }
        else if (s == 1) { X = J.X1; rp = J.rp1; adj = J.adj1; Wt = J.W1; }
        else { X = J.X2; rp = J.rp2; adj = J.adj2; Wt = J.W2; }

        // ---- gather this source's 128-row A tile into frag-layout LDS ----
#pragma unroll
        for (int pass = 0; pass < 128 / NPB; ++pass) {
            int row = pass * NPB + nloc;
            int node = rowBase + row;
            half8v h = {};
            if (node < J.N) {
                if (rp) {
                    int a = rp[node], b = rp[node + 1];
                    float av[8] = {0.f, 0.f, 0.f, 0.f, 0.f, 0.f, 0.f, 0.f};
                    int e = a;
                    for (; e + 2 <= b; e += 2) {
                        int s0 = adj[e], s1 = adj[e + 1];
                        half8v v0 = *reinterpret_cast<const half8v*>(&X[(size_t)s0 * K + glane * 8]);
                        half8v v1 = *reinterpret_cast<const half8v*>(&X[(size_t)s1 * K + glane * 8]);
#pragma unroll
                        for (int i = 0; i < 8; ++i) av[i] += (float)v0[i];
#pragma unroll
                        for (int i = 0; i < 8; ++i) av[i] += (float)v1[i];
                    }
                    if (e < b) {
                        int s0 = adj[e];
                        half8v v0 = *reinterpret_cast<const half8v*>(&X[(size_t)s0 * K + glane * 8]);
#pragma unroll
                        for (int i = 0; i < 8; ++i) av[i] += (float)v0[i];
                    }
#pragma unroll
                    for (int i = 0; i < 8; ++i) h[i] = (_Float16)av[i];
                } else {
                    h = *reinterpret_cast<const half8v*>(&X[(size_t)node * K + glane * 8]);
                }
            }
            int R = (row >> 5) * KS + gt;
            int l = (row & 31) + 32 * gk8;
            *reinterpret_cast<half8v*>(&Alds[(R * 64 + l) * 8]) = h;
        }
        __syncthreads();

        // ---- MFMA sweep over K for this source ----
#pragma unroll
        for (int t = 0; t < KS; ++t) {
            half8v av[2], wv[2];
#pragma unroll
            for (int r = 0; r < 2; ++r) {
                int R = (wr * 2 + r) * KS + t;
                av[r] = *reinterpret_cast<const half8v*>(&Alds[(R * 64 + lane) * 8]);
            }
#pragma unroll
            for (int cc = 0; cc < 2; ++cc) {
                int col = wc * 64 + cc * 32 + (lane & 31);
                wv[cc] = *reinterpret_cast<const half8v*>(
                    &Wt[(size_t)col * K + t * 16 + (lane >> 5) * 8]);
            }
#pragma unroll
            for (int r = 0; r < 2; ++r)
#pragma unroll
                for (int cc = 0; cc < 2; ++cc)
                    acc[r][cc] = __builtin_amdgcn_mfma_f32_32x32x16_f16(wv[cc], av[r], acc[r][cc], 0, 0, 0);
        }
        __syncthreads();
    }

    // ---- epilogue: lane owns one node per C-tile row; coalesced 8 B stores ----
#pragma unroll
    for (int r = 0; r < 2; ++r) {
        int node = rowBase + (wr * 2 + r) * 32 + (lane & 31);
        if (node >= J.N) continue;
        _Float16* orow = J.O + (size_t)node * HID;
#pragma unroll
        for (int cc = 0; cc < 2; ++cc) {
            int fb_ = wc * 64 + cc * 32 + 4 * (lane >> 5);
#pragma unroll
            for (int g = 0; g < 4; ++g) {
                int f = fb_ + g * 8;
                float4 bv = *reinterpret_cast<const float4*>(&J.b0[f]);
                if (J.b1) {
                    float4 b2v = *reinterpret_cast<const float4*>(&J.b1[f]);
                    bv.x += b2v.x; bv.y += b2v.y; bv.z += b2v.z; bv.w += b2v.w;
                }
                half4v hv;
#pragma unroll
                for (int i = 0; i < 4; ++i) {
                    float v = acc[r][cc][g * 4 + i] + ((const float*)&bv)[i];
                    if (RELU) v = fmaxf(v, 0.f);
                    hv[i] = (_Float16)v;
                }
                *reinterpret_cast<half4v*>(&orow[f]) = hv;
            }
        }
    }
}

// ---- segment boundaries for both node types ----
__global__ void seg_bounds2_k(const int* b0, int n0, int* s0,
                              const int* b1, int n1, int* s1, int G) {
    int r = blockIdx.x;
    const int* batch = r == 0 ? b0 : b1;
    int n = r == 0 ? n0 : n1;
    int* starts = r == 0 ? s0 : s1;
    int g = threadIdx.x;
    if (g > G) return;
    int lo = 0, hi = n;
    while (lo < hi) {
        int mid = (lo + hi) >> 1;
        if (batch[mid] < g) lo = mid + 1; else hi = mid;
    }
    starts[g] = lo;
}

// ---- segment max for both node types: grid (G, SUB, 2) ----
__global__ __launch_bounds__(128) void seg_max2_k(const _Float16* H0, const int* st0, unsigned* g0,
                                                  const _Float16* H1, const int* st1, unsigned* g1) {
    int z = blockIdx.z;
    const _Float16* Hf = z == 0 ? H0 : H1;
    const int* starts = z == 0 ? st0 : st1;
    unsigned* gmU = z == 0 ? g0 : g1;
    int g = blockIdx.x;
    int sub = blockIdx.y;
    int SUB = gridDim.y;
    int f = threadIdx.x;
    int s0 = starts[g], s1 = starts[g + 1];
    int len = s1 - s0;
    if (len <= 0) return;
    int chunk = (len + SUB - 1) / SUB;
    int a = s0 + sub * chunk;
    int b = min(a + chunk, s1);
    if (a >= b) return;
    float m = -__builtin_huge_valf();
    for (int n = a; n < b; ++n) m = fmaxf(m, (float)Hf[(size_t)n * HID + f]);
    atomicMax(&gmU[g * HID + f], encf(m));
}

// ---- per-graph MLP heads + final combine ----
__global__ void head_k(const unsigned* __restrict__ gmU_pe, const unsigned* __restrict__ gmU_r,
                       const float* __restrict__ W1, const float* __restrict__ b1,
                       const float* __restrict__ W2, const float* __restrict__ b2,
                       const float* __restrict__ oW, const float* __restrict__ ob,
                       float* __restrict__ out, int G) {
    int g = threadIdx.x;
    if (g >= G) return;
    float vals[2];
#pragma unroll
    for (int t = 0; t < 2; ++t) {
        const unsigned* gm = t ? gmU_r : gmU_pe;
        float z[5];
#pragma unroll
        for (int j = 0; j < 5; ++j) z[j] = b1[t * 5 + j];
        for (int f = 0; f < HID; ++f) {
            float x = decf(gm[g * HID + f]);
#pragma unroll
            for (int j = 0; j < 5; ++j) z[j] = fmaf(x, W1[t * HID * 5 + f * 5 + j], z[j]);
        }
        float o = b2[t];
#pragma unroll
        for (int j = 0; j < 5; ++j) o = fmaf(fmaxf(z[j], 0.f), W2[t * 5 + j], o);
        vals[t] = o;
    }
    out[g] = vals[0] * oW[0] + vals[1] * oW[1] + ob[0];
}

extern "C" void kernel_launch(void* const* d_in, const int* in_sizes, int n_in,
                              void* d_out, int out_size, void* d_ws, size_t ws_size,
                              hipStream_t stream) {
    const float* x_pe    = (const float*)d_in[0];
    const float* x_r     = (const float*)d_in[1];
    const int* ei_per    = (const int*)d_in[2];
    const int* ei_rpe    = (const int*)d_in[3];
    const int* ei_rr     = (const int*)d_in[4];
    const int* batch_pe  = (const int*)d_in[5];
    const int* batch_r   = (const int*)d_in[6];
    const float* Wrel1   = (const float*)d_in[7];
    const float* brel1   = (const float*)d_in[8];
    const float* Wroot1  = (const float*)d_in[9];
    const float* Wrel23  = (const float*)d_in[10];
    const float* brel23  = (const float*)d_in[11];
    const float* Wroot23 = (const float*)d_in[12];
    const float* mlp_W1  = (const float*)d_in[13];
    const float* mlp_b1  = (const float*)d_in[14];
    const float* mlp_W2  = (const float*)d_in[15];
    const float* mlp_b2  = (const float*)d_in[16];
    const float* out_W   = (const float*)d_in[17];
    const float* out_b   = (const float*)d_in[18];
    float* out = (float*)d_out;

    const int N_PE = in_sizes[0] / DIN;
    const int N_R  = in_sizes[1] / DIN;
    const int E    = in_sizes[2] / 2;
    const int G    = out_size;
    const int NMAX = (N_PE > N_R) ? N_PE : N_R;
    const size_t SZM = (size_t)NMAX * HID;

    // ---- workspace layout ----
    _Float16* H1 = (_Float16*)d_ws;
    _Float16* H2 = H1 + SZM;
    _Float16* H3 = H2 + SZM;
    _Float16* H4 = H3 + SZM;
    _Float16* H5 = H4 + SZM;
    _Float16* xh_pe = H5 + SZM;
    _Float16* xh_r  = xh_pe + (size_t)N_PE * DIN;
    float* wsum1 = (float*)(xh_r + (size_t)N_R * DIN);
    float* wsum2 = wsum1 + DIN * HID;
    float* wsum3 = wsum2 + HID * HID;
    _Float16* wt_rel1    = (_Float16*)(wsum3 + HID * HID);
    _Float16* wt_root1pe = wt_rel1 + 3 * DIN * HID;
    _Float16* wt_wsum1   = wt_root1pe + DIN * HID;
    _Float16* wt_rel23   = wt_wsum1 + DIN * HID;
    _Float16* wt_root23  = wt_rel23 + 6 * HID * HID;
    _Float16* wt_wsum2   = wt_root23 + 6 * HID * HID;
    _Float16* wt_wsum3   = wt_wsum2 + HID * HID;
    unsigned* gmU_pe = (unsigned*)(wt_wsum3 + HID * HID);
    unsigned* gmU_r  = gmU_pe + G * HID;
    int* starts_pe = (int*)(gmU_r + G * HID);
    int* starts_r  = starts_pe + (G + 1);
    int* bktCnt = starts_r + (G + 1);            // 3 * NBKMAX
    int* bb     = bktCnt + 3 * NBKMAX;           // 3 * (NBKMAX+1)
    int* gcur   = bb + 3 * (NBKMAX + 1);         // 3 * NBKMAX
    int* csr    = gcur + 3 * NBKMAX;
    const size_t relstride = (size_t)(NMAX + 1) + 2 * (size_t)E + 16;

    int* rp[3]; int* adjp[3]; unsigned* tmp[3];
    const int Nds[3] = {N_R, N_PE, N_R};
    for (int r = 0; r < 3; ++r) {
        int* rowptr = csr + (size_t)r * relstride;
        rp[r] = rowptr;
        adjp[r] = rowptr + (Nds[r] + 1);
        tmp[r] = (unsigned*)(adjp[r] + E);
    }

    const int gpe = (N_PE + 127) / 128, grr = (N_R + 127) / 128;

    // ---- pre-sums ----
    {
        dim3 g((16384 + 255) / 256, 3);
        matadd3_k<<<g, 256, 0, stream>>>(
            Wroot1, Wroot1 + 2 * DIN * HID, wsum1, DIN * HID,
            Wroot23, Wroot23 + 2 * HID * HID, wsum2, HID * HID,
            Wroot23 + 3 * HID * HID, Wroot23 + 5 * HID * HID, wsum3, HID * HID);
    }
    // ---- input conversion ----
    {
        int n40 = N_PE * DIN / 4, n41 = N_R * DIN / 4;
        int nmax = n40 > n41 ? n40 : n41;
        dim3 g((nmax + 255) / 256, 2);
        conv_x2_k<<<g, 256, 0, stream>>>(x_pe, xh_pe, n40, x_r, xh_r, n41);
    }
    // ---- weight conversion ----
    {
        CW c0{Wrel1, wt_rel1, DIN, 3 * DIN * HID};
        CW c1{Wroot1 + 1 * DIN * HID, wt_root1pe, DIN, DIN * HID};
        CW c2{wsum1, wt_wsum1, DIN, DIN * HID};
        CW c3{Wrel23, wt_rel23, HID, 6 * HID * HID};
        CW c4{Wroot23, wt_root23, HID, 6 * HID * HID};
        CW c5{wsum2, wt_wsum2, HID, HID * HID};
        CW c6{wsum3, wt_wsum3, HID, HID * HID};
        dim3 g((6 * HID * HID + 255) / 256, 7);
        conv_w7_k<<<g, 256, 0, stream>>>(c0, c1, c2, c3, c4, c5, c6);
    }
    // ---- CSR build: bucketed counting sort ----
    {
        hipMemsetAsync(bktCnt, 0, 3 * NBKMAX * sizeof(int), stream);
        int eb = (E + EPB - 1) / EPB;
        dim3 gh(eb, 3);
        bhist_k<<<gh, 256, 0, stream>>>(ei_per, ei_rpe, ei_rr, E,
                                        bktCnt, bktCnt + NBKMAX, bktCnt + 2 * NBKMAX);
        bscan_k<<<1, 256, 0, stream>>>(
            bktCnt, bb, gcur, rp[0], Nds[0],
            bktCnt + NBKMAX, bb + (NBKMAX + 1), gcur + NBKMAX, rp[1], Nds[1],
            bktCnt + 2 * NBKMAX, bb + 2 * (NBKMAX + 1), gcur + 2 * NBKMAX, rp[2], Nds[2], E);
        bin_k<<<gh, 256, 0, stream>>>(ei_per, ei_rpe, ei_rr, E,
                                      gcur, gcur + NBKMAX, gcur + 2 * NBKMAX,
                                      tmp[0], tmp[1], tmp[2]);
        dim3 gc(NBKMAX, 3);
        bcsr_k<<<gc, 256, 0, stream>>>(tmp[0], tmp[1], tmp[2],
                                       bb, bb + (NBKMAX + 1), bb + 2 * (NBKMAX + 1),
                                       rp[0], rp[1], rp[2],
                                       adjp[0], adjp[1], adjp[2],
                                       Nds[0], Nds[1], Nds[2]);
    }

    // ---------- layer 1 (K = 64): fused gather+GEMM ----------
    {
        FJob jp{xh_r, rp[1], adjp[1], wt_rel1 + 1 * DIN * HID,
                xh_pe, nullptr, nullptr, wt_root1pe,
                nullptr, nullptr, nullptr, nullptr,
                brel1 + HID, nullptr, H4, N_PE, 2, gpe};
        FJob jr{xh_pe, rp[0], adjp[0], wt_rel1,
                xh_r, rp[2], adjp[2], wt_rel1 + 2 * DIN * HID,
                xh_r, nullptr, nullptr, wt_wsum1,
                brel1, brel1 + 2 * HID, H5, N_R, 3, grr};
        fgemm_k<DIN, true><<<gpe + grr, 256, 0, stream>>>(jp, jr);
    }
    // ---------- layer 2 (K = 128): h_pe=H4, h_r=H5 -> H1, H2 ----------
    {
        FJob jp{H5, rp[1], adjp[1], wt_rel23 + 1 * HID * HID,
                H4, nullptr, nullptr, wt_root23 + 1 * HID * HID,
                nullptr, nullptr, nullptr, nullptr,
                brel23 + HID, nullptr, H1, N_PE, 2, gpe};
        FJob jr{H4, rp[0], adjp[0], wt_rel23,
                H5, rp[2], adjp[2], wt_rel23 + 2 * HID * HID,
                H5, nullptr, nullptr, wt_wsum2,
                brel23, brel23 + 2 * HID, H2, N_R, 3, grr};
        fgemm_k<HID, true><<<gpe + grr, 256, 0, stream>>>(jp, jr);
    }
    // ---------- layer 3 (K = 128): h_pe=H1, h_r=H2 -> H3, H4; no ReLU ----------
    {
        FJob jp{H2, rp[1], adjp[1], wt_rel23 + 4 * HID * HID,
                H1, nullptr, nullptr, wt_root23 + 4 * HID * HID,
                nullptr, nullptr, nullptr, nullptr,
                brel23 + 4 * HID, nullptr, H3, N_PE, 2, gpe};
        FJob jr{H1, rp[0], adjp[0], wt_rel23 + 3 * HID * HID,
                H2, rp[2], adjp[2], wt_rel23 + 5 * HID * HID,
                H2, nullptr, nullptr, wt_wsum3,
                brel23 + 3 * HID, brel23 + 5 * HID, H4, N_R, 3, grr};
        fgemm_k<HID, false><<<gpe + grr, 256, 0, stream>>>(jp, jr);
    }

    // ---------- readout ----------
    seg_bounds2_k<<<2, 128, 0, stream>>>(batch_pe, N_PE, starts_pe, batch_r, N_R, starts_r, G);
    hipMemsetAsync(gmU_pe, 0, 2 * (size_t)G * HID * sizeof(unsigned), stream);
    dim3 gs(G, 16, 2);
    seg_max2_k<<<gs, 128, 0, stream>>>(H3, starts_pe, gmU_pe, H4, starts_r, gmU_r);
    head_k<<<1, 64, 0, stream>>>(gmU_pe, gmU_r, mlp_W1, mlp_b1, mlp_W2, mlp_b2, out_W, out_b, out, G);
}

// Round 8
// 629.424 us; speedup vs baseline: 1.2510x; 1.2510x over previous
//
#include <hip/hip_runtime.h>
#include <cstddef>
#include <cstdint>

#define DIN 64
#define HID 128
#define NBKMAX 256   // max dst buckets of 512 nodes -> supports N <= 131072
#define EPB 2048     // edges per bin-pass block (small: keep many blocks in flight)

typedef _Float16 half4v __attribute__((ext_vector_type(4)));
typedef _Float16 half8v __attribute__((ext_vector_type(8)));
typedef float f32x16 __attribute__((ext_vector_type(16)));

// ---- order-preserving float<->uint for atomicMax-based segment max ----
__device__ __forceinline__ unsigned encf(float f) {
    unsigned b = __float_as_uint(f);
    return (b & 0x80000000u) ? ~b : (b | 0x80000000u);
}
__device__ __forceinline__ float decf(unsigned u) {
    unsigned b = (u & 0x80000000u) ? (u & 0x7FFFFFFFu) : ~u;
    return __uint_as_float(b);
}

// ---- 3 matrix adds in one launch (Wroot pre-sums) ----
__global__ void matadd3_k(const float* a0, const float* b0f, float* o0, int n0,
                          const float* a1, const float* b1f, float* o1, int n1,
                          const float* a2, const float* b2f, float* o2, int n2) {
    int r = blockIdx.y;
    const float* a = r == 0 ? a0 : (r == 1 ? a1 : a2);
    const float* b = r == 0 ? b0f : (r == 1 ? b1f : b2f);
    float* o = r == 0 ? o0 : (r == 1 ? o1 : o2);
    int n = r == 0 ? n0 : (r == 1 ? n1 : n2);
    int i = blockIdx.x * 256 + threadIdx.x;
    if (i < n) o[i] = a[i] + b[i];
}

// ---- fp32 -> f16 for both inputs in one launch ----
__global__ void conv_x2_k(const float* s0, _Float16* d0, int n40,
                          const float* s1, _Float16* d1, int n41) {
    int r = blockIdx.y;
    const float* s = r == 0 ? s0 : s1;
    _Float16* d = r == 0 ? d0 : d1;
    int n4 = r == 0 ? n40 : n41;
    int i = blockIdx.x * 256 + threadIdx.x;
    if (i >= n4) return;
    float4 v = *reinterpret_cast<const float4*>(&s[i * 4]);
    half4v h;
    h.x = (_Float16)v.x; h.y = (_Float16)v.y; h.z = (_Float16)v.z; h.w = (_Float16)v.w;
    *reinterpret_cast<half4v*>(&d[i * 4]) = h;
}

// ---- 7 weight convert+transpose jobs in one launch ----
struct CW { const float* src; _Float16* dst; int K; int total; };
__global__ void conv_w7_k(CW c0, CW c1, CW c2, CW c3, CW c4, CW c5, CW c6) {
    CW J;
    switch (blockIdx.y) {
        case 0: J = c0; break; case 1: J = c1; break; case 2: J = c2; break;
        case 3: J = c3; break; case 4: J = c4; break; case 5: J = c5; break;
        default: J = c6; break;
    }
    int i = blockIdx.x * 256 + threadIdx.x;
    if (i >= J.total) return;
    int m = i / (J.K * HID);
    int rem = i % (J.K * HID);
    int k = rem / HID;
    int col = rem % HID;
    J.dst[(size_t)m * HID * J.K + (size_t)col * J.K + k] = (_Float16)J.src[i];
}

// ================= CSR build via cache-local counting sort =================
__global__ __launch_bounds__(256) void bhist_k(const int* e0, const int* e1, const int* e2, int E,
                                               int* c0, int* c1, int* c2) {
    int r = blockIdx.y;
    const int* ei = r == 0 ? e0 : (r == 1 ? e1 : e2);
    int* cnt = r == 0 ? c0 : (r == 1 ? c1 : c2);
    __shared__ int sc[NBKMAX];
    int t = threadIdx.x;
    sc[t] = 0;
    __syncthreads();
    int base = blockIdx.x * EPB;
    int n = min(EPB, E - base);
    for (int i = t; i < n; i += 256)
        atomicAdd(&sc[(unsigned)ei[E + base + i] >> 9], 1);
    __syncthreads();
    if (sc[t]) atomicAdd(&cnt[t], sc[t]);
}

__global__ __launch_bounds__(256) void bscan_k(int* c0, int* bb0, int* cu0, int* rp0, int n0,
                                               int* c1, int* bb1, int* cu1, int* rp1, int n1,
                                               int* c2, int* bb2, int* cu2, int* rp2, int n2,
                                               int E) {
    __shared__ int sh[256];
    int t = threadIdx.x;
    for (int r = 0; r < 3; ++r) {
        int* cnt = r == 0 ? c0 : (r == 1 ? c1 : c2);
        int* bb  = r == 0 ? bb0 : (r == 1 ? bb1 : bb2);
        int* cu  = r == 0 ? cu0 : (r == 1 ? cu1 : cu2);
        int* rp  = r == 0 ? rp0 : (r == 1 ? rp1 : rp2);
        int N    = r == 0 ? n0 : (r == 1 ? n1 : n2);
        int v = cnt[t];
        sh[t] = v;
        __syncthreads();
        for (int off = 1; off < 256; off <<= 1) {
            int val = (t >= off) ? sh[t - off] : 0;
            __syncthreads();
            sh[t] += val;
            __syncthreads();
        }
        int ex = sh[t] - v;
        bb[t] = ex;
        cu[t] = ex;
        if (t == 255) bb[256] = sh[255];
        if (t == 0) rp[N] = E;
        __syncthreads();
    }
}

__global__ __launch_bounds__(256) void bin_k(const int* e0, const int* e1, const int* e2, int E,
                                             int* cu0, int* cu1, int* cu2,
                                             unsigned* t0, unsigned* t1, unsigned* t2) {
    int r = blockIdx.y;
    const int* ei = r == 0 ? e0 : (r == 1 ? e1 : e2);
    int* gcur = r == 0 ? cu0 : (r == 1 ? cu1 : cu2);
    unsigned* temp = r == 0 ? t0 : (r == 1 ? t1 : t2);
    __shared__ unsigned pk[EPB];
    __shared__ unsigned short bkb[EPB];
    __shared__ int cnt[NBKMAX];
    __shared__ int scn[NBKMAX];
    __shared__ int rb[NBKMAX];
    int t = threadIdx.x;
    int base = blockIdx.x * EPB;
    int n = min(EPB, E - base);
    cnt[t] = 0;
    __syncthreads();
    for (int i = t; i < n; i += 256)
        atomicAdd(&cnt[(unsigned)ei[E + base + i] >> 9], 1);
    __syncthreads();
    {
        int v = cnt[t];
        scn[t] = v;
        __syncthreads();
        for (int off = 1; off < 256; off <<= 1) {
            int val = (t >= off) ? scn[t - off] : 0;
            __syncthreads();
            scn[t] += val;
            __syncthreads();
        }
        int ex = scn[t] - v;
        __syncthreads();
        scn[t] = ex;
    }
    {
        int c = cnt[t];
        rb[t] = c ? atomicAdd(&gcur[t], c) : 0;
        cnt[t] = 0;
    }
    __syncthreads();
    for (int i = t; i < n; i += 256) {
        int s = ei[base + i];
        int d = ei[E + base + i];
        int b = (unsigned)d >> 9;
        int slot = scn[b] + atomicAdd(&cnt[b], 1);
        pk[slot] = ((unsigned)s << 9) | (unsigned)(d & 511);
        bkb[slot] = (unsigned short)b;
    }
    __syncthreads();
    for (int i = t; i < n; i += 256) {
        int b = bkb[i];
        temp[rb[b] + (i - scn[b])] = pk[i];
    }
}

__global__ __launch_bounds__(256) void bcsr_k(const unsigned* t0, const unsigned* t1, const unsigned* t2,
                                              const int* bb0, const int* bb1, const int* bb2,
                                              int* rp0, int* rp1, int* rp2,
                                              int* a0, int* a1, int* a2,
                                              int n0, int n1, int n2) {
    int r = blockIdx.y;
    const unsigned* temp = r == 0 ? t0 : (r == 1 ? t1 : t2);
    const int* bb = r == 0 ? bb0 : (r == 1 ? bb1 : bb2);
    int* rp = r == 0 ? rp0 : (r == 1 ? rp1 : rp2);
    int* adj = r == 0 ? a0 : (r == 1 ? a1 : a2);
    int N = r == 0 ? n0 : (r == 1 ? n1 : n2);
    int b = blockIdx.x;
    int lo = bb[b], hi = bb[b + 1];
    __shared__ int cnt[512];
    __shared__ int sh[256];
    int t = threadIdx.x;
    cnt[t] = 0; cnt[t + 256] = 0;
    __syncthreads();
    for (int i = lo + t; i < hi; i += 256)
        atomicAdd(&cnt[temp[i] & 511], 1);
    __syncthreads();
    int c0 = cnt[2 * t], c1 = cnt[2 * t + 1];
    sh[t] = c0 + c1;
    __syncthreads();
    for (int off = 1; off < 256; off <<= 1) {
        int v = (t >= off) ? sh[t - off] : 0;
        __syncthreads();
        sh[t] += v;
        __syncthreads();
    }
    int pairExcl = sh[t] - (c0 + c1);
    __syncthreads();
    int e0x = lo + pairExcl;
    int e1x = e0x + c0;
    cnt[2 * t] = e0x;
    cnt[2 * t + 1] = e1x;
    int nodeBase = b * 512;
    if (nodeBase + 2 * t < N) rp[nodeBase + 2 * t] = e0x;
    if (nodeBase + 2 * t + 1 < N) rp[nodeBase + 2 * t + 1] = e1x;
    __syncthreads();
    for (int i = lo + t; i < hi; i += 256) {
        unsigned p = temp[i];
        int pos = atomicAdd(&cnt[p & 511], 1);
        adj[pos] = p >> 9;
    }
}

// ---- 3 gather-sum aggregations in one launch (f16, fp32 acc, 4-deep unroll) ----
struct AJob { const _Float16* X; const int* rp; const int* adj; _Float16* AGG; int N; int gb; };
template <int D>
__global__ __launch_bounds__(256) void gather3_k(AJob a0, AJob a1, AJob a2) {
    int b = blockIdx.x;
    AJob J;
    if (b < a0.gb) { J = a0; }
    else if (b < a0.gb + a1.gb) { J = a1; b -= a0.gb; }
    else { J = a2; b -= a0.gb + a1.gb; }
    constexpr int TPN = D / 8;
    constexpr int NPB = 256 / TPN;
    int node = b * NPB + threadIdx.x / TPN;
    int lane = threadIdx.x % TPN;
    if (node >= J.N) return;
    int a = J.rp[node], e1 = J.rp[node + 1];
    float acc[8] = {0.f, 0.f, 0.f, 0.f, 0.f, 0.f, 0.f, 0.f};
    int e = a;
    for (; e + 4 <= e1; e += 4) {
        int s0 = J.adj[e], s1 = J.adj[e + 1], s2 = J.adj[e + 2], s3 = J.adj[e + 3];
        half8v v0 = *reinterpret_cast<const half8v*>(&J.X[(size_t)s0 * D + lane * 8]);
        half8v v1 = *reinterpret_cast<const half8v*>(&J.X[(size_t)s1 * D + lane * 8]);
        half8v v2 = *reinterpret_cast<const half8v*>(&J.X[(size_t)s2 * D + lane * 8]);
        half8v v3 = *reinterpret_cast<const half8v*>(&J.X[(size_t)s3 * D + lane * 8]);
#pragma unroll
        for (int i = 0; i < 8; ++i) acc[i] += (float)v0[i] + (float)v1[i] + (float)v2[i] + (float)v3[i];
    }
    for (; e < e1; ++e) {
        int s0 = J.adj[e];
        half8v v0 = *reinterpret_cast<const half8v*>(&J.X[(size_t)s0 * D + lane * 8]);
#pragma unroll
        for (int i = 0; i < 8; ++i) acc[i] += (float)v0[i];
    }
    half8v o;
#pragma unroll
    for (int i = 0; i < 8; ++i) o[i] = (_Float16)acc[i];
    *reinterpret_cast<half8v*>(&J.AGG[(size_t)node * D + lane * 8]) = o;
}

// ======================= dual-job MFMA GEMM, 64-col chunks =======================
// O[N,128] = sum_s A_s[N,K] @ W_s[K,128] + b0 (+ b1), opt ReLU; f16 act, fp32 acc.
// 64-col chunks: 4x16B independent global loads per thread per chunk (4x ILP vs
// 32-col), 16 MFMA per barrier, double-buffered LDS (2x16KB), 1-chunk prefetch.
// Operand-swapped MFMA -> lane owns 16 features of one node -> coalesced stores.
// In-place O==A_s is safe: each block reads only the rows it writes.
struct GJob {
    const _Float16* A0; const _Float16* A1; const _Float16* A2;
    const _Float16* W0; const _Float16* W1; const _Float16* W2;
    const float* b0; const float* b1;
    _Float16* O;
    int N; int total; int gb;   // total = NA * (K/64)
};

template <bool RELU>
__global__ __launch_bounds__(256) void gemm2_k(GJob j0, GJob j1, int K, int lg) {
    const bool second = ((int)blockIdx.x >= j0.gb);
    const GJob J = second ? j1 : j0;
    const int bx = blockIdx.x - (second ? j0.gb : 0);
    __shared__ _Float16 Alds[2][128 * 64];  // 2 x 16 KB
    const int tid = threadIdx.x;
    const int lane = tid & 63;
    const int w = tid >> 6;
    const int wr = w & 1, wc = w >> 1;
    const int rowBase = bx * 128;

    f32x16 acc[2][2];
#pragma unroll
    for (int r = 0; r < 2; ++r)
#pragma unroll
        for (int c = 0; c < 2; ++c)
#pragma unroll
            for (int q = 0; q < 16; ++q) acc[r][c][q] = 0.0f;

    const _Float16* Ap[3] = {J.A0, J.A1, J.A2};

    // staging: thread -> (row, 32-col half); 4x16B loads cover 64B of the row.
    // frag-ready LDS: region R = (row>>5)*4 + t (t = k16 step), lane slot =
    // (row&31) + 32*k8. Lane-consecutive rows -> conflict-free 16B writes.
    const int row = tid & 127;
    const int kh = (tid >> 7) * 32;
    const int gr = rowBase + row;
    const bool rowOK = (gr < J.N);
    int offW[4];
#pragma unroll
    for (int j = 0; j < 4; ++j) {
        int t = (kh >> 4) + (j >> 1);
        int k8 = j & 1;
        offW[j] = (((row >> 5) * 4 + t) * 64 + (row & 31) + 32 * k8) * 8;
    }

    const int total = J.total;
    const int cmask = (1 << lg) - 1;

    auto ld = [&](int c, half8v h[4]) {
        int s = c >> lg;
        int k0 = (c & cmask) * 64;
        half8v z = {};
        h[0] = z; h[1] = z; h[2] = z; h[3] = z;
        if (rowOK) {
            const _Float16* p = Ap[s] + (size_t)gr * K + k0 + kh;
#pragma unroll
            for (int j = 0; j < 4; ++j) h[j] = *reinterpret_cast<const half8v*>(p + j * 8);
        }
    };

    half8v cur[4], nxt[4];
    ld(0, cur);
#pragma unroll
    for (int j = 0; j < 4; ++j) *reinterpret_cast<half8v*>(&Alds[0][offW[j]]) = cur[j];
    __syncthreads();

    for (int c = 0; c < total; ++c) {
        if (c + 1 < total) ld(c + 1, nxt);
        int s = c >> lg;
        int wk0 = (c & cmask) * 64;
        const _Float16* __restrict__ Wt = (s == 0) ? J.W0 : (s == 1 ? J.W1 : J.W2);
        const _Float16* buf = Alds[c & 1];
#pragma unroll
        for (int t = 0; t < 4; ++t) {
            half8v av[2], wv[2];
#pragma unroll
            for (int r = 0; r < 2; ++r) {
                int R = (wr * 2 + r) * 4 + t;
                av[r] = *reinterpret_cast<const half8v*>(&buf[(R * 64 + lane) * 8]);
            }
#pragma unroll
            for (int cc = 0; cc < 2; ++cc) {
                int col = wc * 64 + cc * 32 + (lane & 31);
                wv[cc] = *reinterpret_cast<const half8v*>(
                    &Wt[(size_t)col * K + wk0 + t * 16 + (lane >> 5) * 8]);
            }
#pragma unroll
            for (int r = 0; r < 2; ++r)
#pragma unroll
                for (int cc = 0; cc < 2; ++cc)
                    acc[r][cc] = __builtin_amdgcn_mfma_f32_32x32x16_f16(wv[cc], av[r], acc[r][cc], 0, 0, 0);
        }
        if (c + 1 < total) {
            _Float16* nb = Alds[(c + 1) & 1];
#pragma unroll
            for (int j = 0; j < 4; ++j) *reinterpret_cast<half8v*>(&nb[offW[j]]) = nxt[j];
        }
        __syncthreads();
    }

    // epilogue: lane owns node = rowBase + tile + (lane&31); coalesced 8 B stores
#pragma unroll
    for (int r = 0; r < 2; ++r) {
        int node = rowBase + (wr * 2 + r) * 32 + (lane & 31);
        if (node >= J.N) continue;
        _Float16* orow = J.O + (size_t)node * HID;
#pragma unroll
        for (int cc = 0; cc < 2; ++cc) {
            int fb_ = wc * 64 + cc * 32 + 4 * (lane >> 5);
#pragma unroll
            for (int g = 0; g < 4; ++g) {
                int f = fb_ + g * 8;
                float4 bv = *reinterpret_cast<const float4*>(&J.b0[f]);
                if (J.b1) {
                    float4 b2v = *reinterpret_cast<const float4*>(&J.b1[f]);
                    bv.x += b2v.x; bv.y += b2v.y; bv.z += b2v.z; bv.w += b2v.w;
                }
                half4v hv;
#pragma unroll
                for (int i = 0; i < 4; ++i) {
                    float v = acc[r][cc][g * 4 + i] + ((const float*)&bv)[i];
                    if (RELU) v = fmaxf(v, 0.f);
                    hv[i] = (_Float16)v;
                }
                *reinterpret_cast<half4v*>(&orow[f]) = hv;
            }
        }
    }
}

// ---- segment boundaries for both node types ----
__global__ void seg_bounds2_k(const int* b0, int n0, int* s0,
                              const int* b1, int n1, int* s1, int G) {
    int r = blockIdx.x;
    const int* batch = r == 0 ? b0 : b1;
    int n = r == 0 ? n0 : n1;
    int* starts = r == 0 ? s0 : s1;
    int g = threadIdx.x;
    if (g > G) return;
    int lo = 0, hi = n;
    while (lo < hi) {
        int mid = (lo + hi) >> 1;
        if (batch[mid] < g) lo = mid + 1; else hi = mid;
    }
    starts[g] = lo;
}

// ---- segment max for both node types: grid (G, SUB, 2) ----
__global__ __launch_bounds__(128) void seg_max2_k(const _Float16* H0, const int* st0, unsigned* g0,
                                                  const _Float16* H1, const int* st1, unsigned* g1) {
    int z = blockIdx.z;
    const _Float16* Hf = z == 0 ? H0 : H1;
    const int* starts = z == 0 ? st0 : st1;
    unsigned* gmU = z == 0 ? g0 : g1;
    int g = blockIdx.x;
    int sub = blockIdx.y;
    int SUB = gridDim.y;
    int f = threadIdx.x;
    int s0 = starts[g], s1 = starts[g + 1];
    int len = s1 - s0;
    if (len <= 0) return;
    int chunk = (len + SUB - 1) / SUB;
    int a = s0 + sub * chunk;
    int b = min(a + chunk, s1);
    if (a >= b) return;
    float m = -__builtin_huge_valf();
    for (int n = a; n < b; ++n) m = fmaxf(m, (float)Hf[(size_t)n * HID + f]);
    atomicMax(&gmU[g * HID + f], encf(m));
}

// ---- per-graph MLP heads + final combine ----
__global__ void head_k(const unsigned* __restrict__ gmU_pe, const unsigned* __restrict__ gmU_r,
                       const float* __restrict__ W1, const float* __restrict__ b1,
                       const float* __restrict__ W2, const float* __restrict__ b2,
                       const float* __restrict__ oW, const float* __restrict__ ob,
                       float* __restrict__ out, int G) {
    int g = threadIdx.x;
    if (g >= G) return;
    float vals[2];
#pragma unroll
    for (int t = 0; t < 2; ++t) {
        const unsigned* gm = t ? gmU_r : gmU_pe;
        float z[5];
#pragma unroll
        for (int j = 0; j < 5; ++j) z[j] = b1[t * 5 + j];
        for (int f = 0; f < HID; ++f) {
            float x = decf(gm[g * HID + f]);
#pragma unroll
            for (int j = 0; j < 5; ++j) z[j] = fmaf(x, W1[t * HID * 5 + f * 5 + j], z[j]);
        }
        float o = b2[t];
#pragma unroll
        for (int j = 0; j < 5; ++j) o = fmaf(fmaxf(z[j], 0.f), W2[t * 5 + j], o);
        vals[t] = o;
    }
    out[g] = vals[0] * oW[0] + vals[1] * oW[1] + ob[0];
}

extern "C" void kernel_launch(void* const* d_in, const int* in_sizes, int n_in,
                              void* d_out, int out_size, void* d_ws, size_t ws_size,
                              hipStream_t stream) {
    const float* x_pe    = (const float*)d_in[0];
    const float* x_r     = (const float*)d_in[1];
    const int* ei_per    = (const int*)d_in[2];
    const int* ei_rpe    = (const int*)d_in[3];
    const int* ei_rr     = (const int*)d_in[4];
    const int* batch_pe  = (const int*)d_in[5];
    const int* batch_r   = (const int*)d_in[6];
    const float* Wrel1   = (const float*)d_in[7];
    const float* brel1   = (const float*)d_in[8];
    const float* Wroot1  = (const float*)d_in[9];
    const float* Wrel23  = (const float*)d_in[10];
    const float* brel23  = (const float*)d_in[11];
    const float* Wroot23 = (const float*)d_in[12];
    const float* mlp_W1  = (const float*)d_in[13];
    const float* mlp_b1  = (const float*)d_in[14];
    const float* mlp_W2  = (const float*)d_in[15];
    const float* mlp_b2  = (const float*)d_in[16];
    const float* out_W   = (const float*)d_in[17];
    const float* out_b   = (const float*)d_in[18];
    float* out = (float*)d_out;

    const int N_PE = in_sizes[0] / DIN;
    const int N_R  = in_sizes[1] / DIN;
    const int E    = in_sizes[2] / 2;
    const int G    = out_size;
    const int NMAX = (N_PE > N_R) ? N_PE : N_R;
    const size_t SZM = (size_t)NMAX * HID;

    // ---- workspace layout ----
    _Float16* H1 = (_Float16*)d_ws;
    _Float16* H2 = H1 + SZM;
    _Float16* H3 = H2 + SZM;
    _Float16* H4 = H3 + SZM;
    _Float16* H5 = H4 + SZM;
    _Float16* xh_pe = H5 + SZM;
    _Float16* xh_r  = xh_pe + (size_t)N_PE * DIN;
    float* wsum1 = (float*)(xh_r + (size_t)N_R * DIN);
    float* wsum2 = wsum1 + DIN * HID;
    float* wsum3 = wsum2 + HID * HID;
    _Float16* wt_rel1    = (_Float16*)(wsum3 + HID * HID);
    _Float16* wt_root1pe = wt_rel1 + 3 * DIN * HID;
    _Float16* wt_wsum1   = wt_root1pe + DIN * HID;
    _Float16* wt_rel23   = wt_wsum1 + DIN * HID;
    _Float16* wt_root23  = wt_rel23 + 6 * HID * HID;
    _Float16* wt_wsum2   = wt_root23 + 6 * HID * HID;
    _Float16* wt_wsum3   = wt_wsum2 + HID * HID;
    unsigned* gmU_pe = (unsigned*)(wt_wsum3 + HID * HID);
    unsigned* gmU_r  = gmU_pe + G * HID;
    int* starts_pe = (int*)(gmU_r + G * HID);
    int* starts_r  = starts_pe + (G + 1);
    int* bktCnt = starts_r + (G + 1);            // 3 * NBKMAX
    int* bb     = bktCnt + 3 * NBKMAX;           // 3 * (NBKMAX+1)
    int* gcur   = bb + 3 * (NBKMAX + 1);         // 3 * NBKMAX
    int* csr    = gcur + 3 * NBKMAX;
    const size_t relstride = (size_t)(NMAX + 1) + 2 * (size_t)E + 16;

    int* rp[3]; int* adjp[3]; unsigned* tmp[3];
    const int Nds[3] = {N_R, N_PE, N_R};
    for (int r = 0; r < 3; ++r) {
        int* rowptr = csr + (size_t)r * relstride;
        rp[r] = rowptr;
        adjp[r] = rowptr + (Nds[r] + 1);
        tmp[r] = (unsigned*)(adjp[r] + E);
    }

    const int gpe = (N_PE + 127) / 128, grr = (N_R + 127) / 128;

    // ---- pre-sums ----
    {
        dim3 g((16384 + 255) / 256, 3);
        matadd3_k<<<g, 256, 0, stream>>>(
            Wroot1, Wroot1 + 2 * DIN * HID, wsum1, DIN * HID,
            Wroot23, Wroot23 + 2 * HID * HID, wsum2, HID * HID,
            Wroot23 + 3 * HID * HID, Wroot23 + 5 * HID * HID, wsum3, HID * HID);
    }
    // ---- input conversion ----
    {
        int n40 = N_PE * DIN / 4, n41 = N_R * DIN / 4;
        int nmax = n40 > n41 ? n40 : n41;
        dim3 g((nmax + 255) / 256, 2);
        conv_x2_k<<<g, 256, 0, stream>>>(x_pe, xh_pe, n40, x_r, xh_r, n41);
    }
    // ---- weight conversion ----
    {
        CW c0{Wrel1, wt_rel1, DIN, 3 * DIN * HID};
        CW c1{Wroot1 + 1 * DIN * HID, wt_root1pe, DIN, DIN * HID};
        CW c2{wsum1, wt_wsum1, DIN, DIN * HID};
        CW c3{Wrel23, wt_rel23, HID, 6 * HID * HID};
        CW c4{Wroot23, wt_root23, HID, 6 * HID * HID};
        CW c5{wsum2, wt_wsum2, HID, HID * HID};
        CW c6{wsum3, wt_wsum3, HID, HID * HID};
        dim3 g((6 * HID * HID + 255) / 256, 7);
        conv_w7_k<<<g, 256, 0, stream>>>(c0, c1, c2, c3, c4, c5, c6);
    }
    // ---- CSR build: bucketed counting sort ----
    {
        hipMemsetAsync(bktCnt, 0, 3 * NBKMAX * sizeof(int), stream);
        int eb = (E + EPB - 1) / EPB;
        dim3 gh(eb, 3);
        bhist_k<<<gh, 256, 0, stream>>>(ei_per, ei_rpe, ei_rr, E,
                                        bktCnt, bktCnt + NBKMAX, bktCnt + 2 * NBKMAX);
        bscan_k<<<1, 256, 0, stream>>>(
            bktCnt, bb, gcur, rp[0], Nds[0],
            bktCnt + NBKMAX, bb + (NBKMAX + 1), gcur + NBKMAX, rp[1], Nds[1],
            bktCnt + 2 * NBKMAX, bb + 2 * (NBKMAX + 1), gcur + 2 * NBKMAX, rp[2], Nds[2], E);
        bin_k<<<gh, 256, 0, stream>>>(ei_per, ei_rpe, ei_rr, E,
                                      gcur, gcur + NBKMAX, gcur + 2 * NBKMAX,
                                      tmp[0], tmp[1], tmp[2]);
        dim3 gc(NBKMAX, 3);
        bcsr_k<<<gc, 256, 0, stream>>>(tmp[0], tmp[1], tmp[2],
                                       bb, bb + (NBKMAX + 1), bb + 2 * (NBKMAX + 1),
                                       rp[0], rp[1], rp[2],
                                       adjp[0], adjp[1], adjp[2],
                                       Nds[0], Nds[1], Nds[2]);
    }

    // ---------- layer 1 (K = 64) ----------
    {
        AJob a0{xh_r, rp[1], adjp[1], H1, N_PE, (N_PE + 31) / 32};
        AJob a1{xh_pe, rp[0], adjp[0], H2, N_R, (N_R + 31) / 32};
        AJob a2{xh_r, rp[2], adjp[2], H3, N_R, (N_R + 31) / 32};
        gather3_k<DIN><<<a0.gb + a1.gb + a2.gb, 256, 0, stream>>>(a0, a1, a2);
        GJob jp{H1, xh_pe, nullptr,
                wt_rel1 + 1 * DIN * HID, wt_root1pe, nullptr,
                brel1 + HID, nullptr, H4, N_PE, 2, gpe};
        GJob jr{H2, H3, xh_r,
                wt_rel1, wt_rel1 + 2 * DIN * HID, wt_wsum1,
                brel1, brel1 + 2 * HID, H5, N_R, 3, grr};
        gemm2_k<true><<<gpe + grr, 256, 0, stream>>>(jp, jr, DIN, 0);
    }
    // ---------- layer 2 (K = 128) ----------
    {
        AJob a0{H5, rp[1], adjp[1], H1, N_PE, (N_PE + 15) / 16};
        AJob a1{H4, rp[0], adjp[0], H2, N_R, (N_R + 15) / 16};
        AJob a2{H5, rp[2], adjp[2], H3, N_R, (N_R + 15) / 16};
        gather3_k<HID><<<a0.gb + a1.gb + a2.gb, 256, 0, stream>>>(a0, a1, a2);
        GJob jp{H1, H4, nullptr,
                wt_rel23 + 1 * HID * HID, wt_root23 + 1 * HID * HID, nullptr,
                brel23 + HID, nullptr, H1, N_PE, 2 * 2, gpe};
        GJob jr{H2, H3, H5,
                wt_rel23, wt_rel23 + 2 * HID * HID, wt_wsum2,
                brel23, brel23 + 2 * HID, H2, N_R, 3 * 2, grr};
        gemm2_k<true><<<gpe + grr, 256, 0, stream>>>(jp, jr, HID, 1);
    }
    // ---------- layer 3 (K = 128), no ReLU ----------
    {
        AJob a0{H2, rp[1], adjp[1], H3, N_PE, (N_PE + 15) / 16};
        AJob a1{H1, rp[0], adjp[0], H4, N_R, (N_R + 15) / 16};
        AJob a2{H2, rp[2], adjp[2], H5, N_R, (N_R + 15) / 16};
        gather3_k<HID><<<a0.gb + a1.gb + a2.gb, 256, 0, stream>>>(a0, a1, a2);
        GJob jp{H3, H1, nullptr,
                wt_rel23 + 4 * HID * HID, wt_root23 + 4 * HID * HID, nullptr,
                brel23 + 4 * HID, nullptr, H3, N_PE, 2 * 2, gpe};
        GJob jr{H4, H5, H2,
                wt_rel23 + 3 * HID * HID, wt_rel23 + 5 * HID * HID, wt_wsum3,
                brel23 + 3 * HID, brel23 + 5 * HID, H4, N_R, 3 * 2, grr};
        gemm2_k<false><<<gpe + grr, 256, 0, stream>>>(jp, jr, HID, 1);
    }

    // ---------- readout ----------
    seg_bounds2_k<<<2, 128, 0, stream>>>(batch_pe, N_PE, starts_pe, batch_r, N_R, starts_r, G);
    hipMemsetAsync(gmU_pe, 0, 2 * (size_t)G * HID * sizeof(unsigned), stream);
    dim3 gs(G, 16, 2);
    seg_max2_k<<<gs, 128, 0, stream>>>(H3, starts_pe, gmU_pe, H4, starts_r, gmU_r);
    head_k<<<1, 64, 0, stream>>>(gmU_pe, gmU_r, mlp_W1, mlp_b1, mlp_W2, mlp_b2, out_W, out_b, out, G);
}

// Round 9
// 622.738 us; speedup vs baseline: 1.2644x; 1.0107x over previous
//
#include <hip/hip_runtime.h>
#include <cstddef>
#include <cstdint>

#define DIN 64
#define HID 128
#define NBKMAX 256   // max dst buckets of 512 nodes -> supports N <= 131072
#define EPB 2048     // edges per bin-pass block

typedef _Float16 half4v __attribute__((ext_vector_type(4)));
typedef _Float16 half8v __attribute__((ext_vector_type(8)));
typedef float f32x16 __attribute__((ext_vector_type(16)));

// ---- order-preserving float<->uint for atomicMax-based segment max ----
__device__ __forceinline__ unsigned encf(float f) {
    unsigned b = __float_as_uint(f);
    return (b & 0x80000000u) ? ~b : (b | 0x80000000u);
}
__device__ __forceinline__ float decf(unsigned u) {
    unsigned b = (u & 0x80000000u) ? (u & 0x7FFFFFFFu) : ~u;
    return __uint_as_float(b);
}

// ---- fp32 -> f16 for both inputs in one launch ----
__global__ void conv_x2_k(const float* s0, _Float16* d0, int n40,
                          const float* s1, _Float16* d1, int n41) {
    int r = blockIdx.y;
    const float* s = r == 0 ? s0 : s1;
    _Float16* d = r == 0 ? d0 : d1;
    int n4 = r == 0 ? n40 : n41;
    int i = blockIdx.x * 256 + threadIdx.x;
    if (i >= n4) return;
    float4 v = *reinterpret_cast<const float4*>(&s[i * 4]);
    half4v h;
    h.x = (_Float16)v.x; h.y = (_Float16)v.y; h.z = (_Float16)v.z; h.w = (_Float16)v.w;
    *reinterpret_cast<half4v*>(&d[i * 4]) = h;
}

// ---- 8 weight convert(+add)+transpose jobs: src [M][K][128] (+src2) -> [M][128][K] f16 ----
struct CW { const float* src; const float* src2; _Float16* dst; int K; int total; };
__global__ void conv_w8_k(CW c0, CW c1, CW c2, CW c3, CW c4, CW c5, CW c6, CW c7) {
    CW J;
    switch (blockIdx.y) {
        case 0: J = c0; break; case 1: J = c1; break; case 2: J = c2; break;
        case 3: J = c3; break; case 4: J = c4; break; case 5: J = c5; break;
        case 6: J = c6; break; default: J = c7; break;
    }
    int i = blockIdx.x * 256 + threadIdx.x;
    if (i >= J.total) return;
    int m = i / (J.K * HID);
    int rem = i % (J.K * HID);
    int k = rem / HID;
    int col = rem % HID;
    float v = J.src[i];
    if (J.src2) v += J.src2[i];
    J.dst[(size_t)m * HID * J.K + (size_t)col * J.K + k] = (_Float16)v;
}

// ================= CSR build via cache-local counting sort =================
__global__ __launch_bounds__(256) void bhist_k(const int* e0, const int* e1, const int* e2, int E,
                                               int* c0, int* c1, int* c2) {
    int r = blockIdx.y;
    const int* ei = r == 0 ? e0 : (r == 1 ? e1 : e2);
    int* cnt = r == 0 ? c0 : (r == 1 ? c1 : c2);
    __shared__ int sc[NBKMAX];
    int t = threadIdx.x;
    sc[t] = 0;
    __syncthreads();
    int base = blockIdx.x * EPB;
    int n = min(EPB, E - base);
    for (int i = t; i < n; i += 256)
        atomicAdd(&sc[(unsigned)ei[E + base + i] >> 9], 1);
    __syncthreads();
    if (sc[t]) atomicAdd(&cnt[t], sc[t]);
}

__global__ __launch_bounds__(256) void bscan_k(int* c0, int* bb0, int* cu0, int* rp0, int n0,
                                               int* c1, int* bb1, int* cu1, int* rp1, int n1,
                                               int* c2, int* bb2, int* cu2, int* rp2, int n2,
                                               int E) {
    __shared__ int sh[256];
    int t = threadIdx.x;
    for (int r = 0; r < 3; ++r) {
        int* cnt = r == 0 ? c0 : (r == 1 ? c1 : c2);
        int* bb  = r == 0 ? bb0 : (r == 1 ? bb1 : bb2);
        int* cu  = r == 0 ? cu0 : (r == 1 ? cu1 : cu2);
        int* rp  = r == 0 ? rp0 : (r == 1 ? rp1 : rp2);
        int N    = r == 0 ? n0 : (r == 1 ? n1 : n2);
        int v = cnt[t];
        sh[t] = v;
        __syncthreads();
        for (int off = 1; off < 256; off <<= 1) {
            int val = (t >= off) ? sh[t - off] : 0;
            __syncthreads();
            sh[t] += val;
            __syncthreads();
        }
        int ex = sh[t] - v;
        bb[t] = ex;
        cu[t] = ex;
        if (t == 255) bb[256] = sh[255];
        if (t == 0) rp[N] = E;
        __syncthreads();
    }
}

__global__ __launch_bounds__(256) void bin_k(const int* e0, const int* e1, const int* e2, int E,
                                             int* cu0, int* cu1, int* cu2,
                                             unsigned* t0, unsigned* t1, unsigned* t2) {
    int r = blockIdx.y;
    const int* ei = r == 0 ? e0 : (r == 1 ? e1 : e2);
    int* gcur = r == 0 ? cu0 : (r == 1 ? cu1 : cu2);
    unsigned* temp = r == 0 ? t0 : (r == 1 ? t1 : t2);
    __shared__ unsigned pk[EPB];
    __shared__ unsigned short bkb[EPB];
    __shared__ int cnt[NBKMAX];
    __shared__ int scn[NBKMAX];
    __shared__ int rb[NBKMAX];
    int t = threadIdx.x;
    int base = blockIdx.x * EPB;
    int n = min(EPB, E - base);
    cnt[t] = 0;
    __syncthreads();
    for (int i = t; i < n; i += 256)
        atomicAdd(&cnt[(unsigned)ei[E + base + i] >> 9], 1);
    __syncthreads();
    {
        int v = cnt[t];
        scn[t] = v;
        __syncthreads();
        for (int off = 1; off < 256; off <<= 1) {
            int val = (t >= off) ? scn[t - off] : 0;
            __syncthreads();
            scn[t] += val;
            __syncthreads();
        }
        int ex = scn[t] - v;
        __syncthreads();
        scn[t] = ex;
    }
    {
        int c = cnt[t];
        rb[t] = c ? atomicAdd(&gcur[t], c) : 0;
        cnt[t] = 0;
    }
    __syncthreads();
    for (int i = t; i < n; i += 256) {
        int s = ei[base + i];
        int d = ei[E + base + i];
        int b = (unsigned)d >> 9;
        int slot = scn[b] + atomicAdd(&cnt[b], 1);
        pk[slot] = ((unsigned)s << 9) | (unsigned)(d & 511);
        bkb[slot] = (unsigned short)b;
    }
    __syncthreads();
    for (int i = t; i < n; i += 256) {
        int b = bkb[i];
        temp[rb[b] + (i - scn[b])] = pk[i];
    }
}

__global__ __launch_bounds__(256) void bcsr_k(const unsigned* t0, const unsigned* t1, const unsigned* t2,
                                              const int* bb0, const int* bb1, const int* bb2,
                                              int* rp0, int* rp1, int* rp2,
                                              int* a0, int* a1, int* a2,
                                              int n0, int n1, int n2) {
    int r = blockIdx.y;
    const unsigned* temp = r == 0 ? t0 : (r == 1 ? t1 : t2);
    const int* bb = r == 0 ? bb0 : (r == 1 ? bb1 : bb2);
    int* rp = r == 0 ? rp0 : (r == 1 ? rp1 : rp2);
    int* adj = r == 0 ? a0 : (r == 1 ? a1 : a2);
    int N = r == 0 ? n0 : (r == 1 ? n1 : n2);
    int b = blockIdx.x;
    int lo = bb[b], hi = bb[b + 1];
    __shared__ int cnt[512];
    __shared__ int sh[256];
    int t = threadIdx.x;
    cnt[t] = 0; cnt[t + 256] = 0;
    __syncthreads();
    for (int i = lo + t; i < hi; i += 256)
        atomicAdd(&cnt[temp[i] & 511], 1);
    __syncthreads();
    int c0 = cnt[2 * t], c1 = cnt[2 * t + 1];
    sh[t] = c0 + c1;
    __syncthreads();
    for (int off = 1; off < 256; off <<= 1) {
        int v = (t >= off) ? sh[t - off] : 0;
        __syncthreads();
        sh[t] += v;
        __syncthreads();
    }
    int pairExcl = sh[t] - (c0 + c1);
    __syncthreads();
    int e0x = lo + pairExcl;
    int e1x = e0x + c0;
    cnt[2 * t] = e0x;
    cnt[2 * t + 1] = e1x;
    int nodeBase = b * 512;
    if (nodeBase + 2 * t < N) rp[nodeBase + 2 * t] = e0x;
    if (nodeBase + 2 * t + 1 < N) rp[nodeBase + 2 * t + 1] = e1x;
    __syncthreads();
    for (int i = lo + t; i < hi; i += 256) {
        unsigned p = temp[i];
        int pos = atomicAdd(&cnt[p & 511], 1);
        adj[pos] = p >> 9;
    }
}

// ---- 3 gather-sum aggregations in one launch (f16, fp32 acc, 4-deep unroll) ----
struct AJob { const _Float16* X; const int* rp; const int* adj; _Float16* AGG; int N; int gb; };
template <int D>
__global__ __launch_bounds__(256) void gather3_k(AJob a0, AJob a1, AJob a2) {
    int b = blockIdx.x;
    AJob J;
    if (b < a0.gb) { J = a0; }
    else if (b < a0.gb + a1.gb) { J = a1; b -= a0.gb; }
    else { J = a2; b -= a0.gb + a1.gb; }
    constexpr int TPN = D / 8;
    constexpr int NPB = 256 / TPN;
    int node = b * NPB + threadIdx.x / TPN;
    int lane = threadIdx.x % TPN;
    if (node >= J.N) return;
    int a = J.rp[node], e1 = J.rp[node + 1];
    float acc[8] = {0.f, 0.f, 0.f, 0.f, 0.f, 0.f, 0.f, 0.f};
    int e = a;
    for (; e + 4 <= e1; e += 4) {
        int s0 = J.adj[e], s1 = J.adj[e + 1], s2 = J.adj[e + 2], s3 = J.adj[e + 3];
        half8v v0 = *reinterpret_cast<const half8v*>(&J.X[(size_t)s0 * D + lane * 8]);
        half8v v1 = *reinterpret_cast<const half8v*>(&J.X[(size_t)s1 * D + lane * 8]);
        half8v v2 = *reinterpret_cast<const half8v*>(&J.X[(size_t)s2 * D + lane * 8]);
        half8v v3 = *reinterpret_cast<const half8v*>(&J.X[(size_t)s3 * D + lane * 8]);
#pragma unroll
        for (int i = 0; i < 8; ++i) acc[i] += (float)v0[i] + (float)v1[i] + (float)v2[i] + (float)v3[i];
    }
    for (; e < e1; ++e) {
        int s0 = J.adj[e];
        half8v v0 = *reinterpret_cast<const half8v*>(&J.X[(size_t)s0 * D + lane * 8]);
#pragma unroll
        for (int i = 0; i < 8; ++i) acc[i] += (float)v0[i];
    }
    half8v o;
#pragma unroll
    for (int i = 0; i < 8; ++i) o[i] = (_Float16)acc[i];
    *reinterpret_cast<half8v*>(&J.AGG[(size_t)node * D + lane * 8]) = o;
}

// ======================= dual-job MFMA GEMM, W staged in LDS =======================
// O[N,128] = sum_s A_s[N,K] @ W_s[K,128] + b0 (+ b1), opt ReLU; f16 act, fp32 acc.
// 64-k chunks. Per chunk: A tile (128x64, 16 KB) AND W chunk (128 cols x 64 k,
// 16 KB) staged into LDS in frag-ready layout -> MFMA reads both operands from
// the LDS pipe; global vmem carries only A (98 KB/blk), W (96 KB/blk), stores.
// Single-buffered, 2 barriers/chunk; 32 KB LDS -> ~4-5 blocks/CU for overlap.
// In-place O==A_s is safe: each block reads only the rows it writes.
struct GJob {
    const _Float16* A0; const _Float16* A1; const _Float16* A2;
    const _Float16* W0; const _Float16* W1; const _Float16* W2;
    const float* b0; const float* b1;
    _Float16* O;
    int N; int total; int gb;   // total = NA * (K/64)
};

template <bool RELU>
__global__ __launch_bounds__(256) void gemm2_k(GJob j0, GJob j1, int K, int lg) {
    const bool second = ((int)blockIdx.x >= j0.gb);
    const GJob J = second ? j1 : j0;
    const int bx = blockIdx.x - (second ? j0.gb : 0);
    __shared__ _Float16 Alds[128 * 64];   // 16 KB
    __shared__ _Float16 Wlds[128 * 64];   // 16 KB
    const int tid = threadIdx.x;
    const int lane = tid & 63;
    const int w = tid >> 6;
    const int wr = w & 1, wc = w >> 1;
    const int rowBase = bx * 128;

    f32x16 acc[2][2];
#pragma unroll
    for (int r = 0; r < 2; ++r)
#pragma unroll
        for (int c = 0; c < 2; ++c)
#pragma unroll
            for (int q = 0; q < 16; ++q) acc[r][c][q] = 0.0f;

    const _Float16* Ap[3] = {J.A0, J.A1, J.A2};

    // staging map (shared by A rows and W cols): idx = tid&127, k-half = (tid>>7)*32.
    // frag region R = (idx>>5)*4 + t, slot = (idx&31) + 32*k8 -> 16 B per store,
    // lane-consecutive -> conflict-free.
    const int row = tid & 127;
    const int kh = (tid >> 7) * 32;
    const int gr = rowBase + row;
    const bool rowOK = (gr < J.N);
    int offS[4];
#pragma unroll
    for (int j = 0; j < 4; ++j) {
        int t = (kh >> 4) + (j >> 1);
        int k8 = j & 1;
        offS[j] = (((row >> 5) * 4 + t) * 64 + (row & 31) + 32 * k8) * 8;
    }

    const int total = J.total;
    const int cmask = (1 << lg) - 1;

    auto ldA = [&](int c, half8v h[4]) {
        int s = c >> lg;
        int k0 = (c & cmask) * 64;
        half8v z = {};
        h[0] = z; h[1] = z; h[2] = z; h[3] = z;
        if (rowOK) {
            const _Float16* p = Ap[s] + (size_t)gr * K + k0 + kh;
#pragma unroll
            for (int j = 0; j < 4; ++j) h[j] = *reinterpret_cast<const half8v*>(p + j * 8);
        }
    };
    auto ldW = [&](int c, half8v h[4]) {
        int s = c >> lg;
        int k0 = (c & cmask) * 64;
        const _Float16* __restrict__ Wt = (s == 0) ? J.W0 : (s == 1 ? J.W1 : J.W2);
        const _Float16* p = Wt + (size_t)row * K + k0 + kh;   // row == col index here
#pragma unroll
        for (int j = 0; j < 4; ++j) h[j] = *reinterpret_cast<const half8v*>(p + j * 8);
    };

    half8v ra[4], rw[4];
    ldA(0, ra); ldW(0, rw);
#pragma unroll
    for (int j = 0; j < 4; ++j) {
        *reinterpret_cast<half8v*>(&Alds[offS[j]]) = ra[j];
        *reinterpret_cast<half8v*>(&Wlds[offS[j]]) = rw[j];
    }
    __syncthreads();

    for (int c = 0; c < total; ++c) {
        const bool more = (c + 1 < total);
        if (more) { ldA(c + 1, ra); ldW(c + 1, rw); }
#pragma unroll
        for (int t = 0; t < 4; ++t) {
            half8v av[2], wv[2];
#pragma unroll
            for (int r = 0; r < 2; ++r)
                av[r] = *reinterpret_cast<const half8v*>(&Alds[(((wr * 2 + r) * 4 + t) * 64 + lane) * 8]);
#pragma unroll
            for (int cc = 0; cc < 2; ++cc)
                wv[cc] = *reinterpret_cast<const half8v*>(&Wlds[(((wc * 2 + cc) * 4 + t) * 64 + lane) * 8]);
#pragma unroll
            for (int r = 0; r < 2; ++r)
#pragma unroll
                for (int cc = 0; cc < 2; ++cc)
                    acc[r][cc] = __builtin_amdgcn_mfma_f32_32x32x16_f16(wv[cc], av[r], acc[r][cc], 0, 0, 0);
        }
        __syncthreads();
        if (more) {
#pragma unroll
            for (int j = 0; j < 4; ++j) {
                *reinterpret_cast<half8v*>(&Alds[offS[j]]) = ra[j];
                *reinterpret_cast<half8v*>(&Wlds[offS[j]]) = rw[j];
            }
            __syncthreads();
        }
    }

    // epilogue: lane owns node = rowBase + tile + (lane&31); coalesced 8 B stores
#pragma unroll
    for (int r = 0; r < 2; ++r) {
        int node = rowBase + (wr * 2 + r) * 32 + (lane & 31);
        if (node >= J.N) continue;
        _Float16* orow = J.O + (size_t)node * HID;
#pragma unroll
        for (int cc = 0; cc < 2; ++cc) {
            int fb_ = wc * 64 + cc * 32 + 4 * (lane >> 5);
#pragma unroll
            for (int g = 0; g < 4; ++g) {
                int f = fb_ + g * 8;
                float4 bv = *reinterpret_cast<const float4*>(&J.b0[f]);
                if (J.b1) {
                    float4 b2v = *reinterpret_cast<const float4*>(&J.b1[f]);
                    bv.x += b2v.x; bv.y += b2v.y; bv.z += b2v.z; bv.w += b2v.w;
                }
                half4v hv;
#pragma unroll
                for (int i = 0; i < 4; ++i) {
                    float v = acc[r][cc][g * 4 + i] + ((const float*)&bv)[i];
                    if (RELU) v = fmaxf(v, 0.f);
                    hv[i] = (_Float16)v;
                }
                *reinterpret_cast<half4v*>(&orow[f]) = hv;
            }
        }
    }
}

// ---- segment boundaries for both node types ----
__global__ void seg_bounds2_k(const int* b0, int n0, int* s0,
                              const int* b1, int n1, int* s1, int G) {
    int r = blockIdx.x;
    const int* batch = r == 0 ? b0 : b1;
    int n = r == 0 ? n0 : n1;
    int* starts = r == 0 ? s0 : s1;
    int g = threadIdx.x;
    if (g > G) return;
    int lo = 0, hi = n;
    while (lo < hi) {
        int mid = (lo + hi) >> 1;
        if (batch[mid] < g) lo = mid + 1; else hi = mid;
    }
    starts[g] = lo;
}

// ---- segment max for both node types: grid (G, SUB, 2) ----
__global__ __launch_bounds__(128) void seg_max2_k(const _Float16* H0, const int* st0, unsigned* g0,
                                                  const _Float16* H1, const int* st1, unsigned* g1) {
    int z = blockIdx.z;
    const _Float16* Hf = z == 0 ? H0 : H1;
    const int* starts = z == 0 ? st0 : st1;
    unsigned* gmU = z == 0 ? g0 : g1;
    int g = blockIdx.x;
    int sub = blockIdx.y;
    int SUB = gridDim.y;
    int f = threadIdx.x;
    int s0 = starts[g], s1 = starts[g + 1];
    int len = s1 - s0;
    if (len <= 0) return;
    int chunk = (len + SUB - 1) / SUB;
    int a = s0 + sub * chunk;
    int b = min(a + chunk, s1);
    if (a >= b) return;
    float m = -__builtin_huge_valf();
    for (int n = a; n < b; ++n) m = fmaxf(m, (float)Hf[(size_t)n * HID + f]);
    atomicMax(&gmU[g * HID + f], encf(m));
}

// ---- per-graph MLP heads + final combine ----
__global__ void head_k(const unsigned* __restrict__ gmU_pe, const unsigned* __restrict__ gmU_r,
                       const float* __restrict__ W1, const float* __restrict__ b1,
                       const float* __restrict__ W2, const float* __restrict__ b2,
                       const float* __restrict__ oW, const float* __restrict__ ob,
                       float* __restrict__ out, int G) {
    int g = threadIdx.x;
    if (g >= G) return;
    float vals[2];
#pragma unroll
    for (int t = 0; t < 2; ++t) {
        const unsigned* gm = t ? gmU_r : gmU_pe;
        float z[5];
#pragma unroll
        for (int j = 0; j < 5; ++j) z[j] = b1[t * 5 + j];
        for (int f = 0; f < HID; ++f) {
            float x = decf(gm[g * HID + f]);
#pragma unroll
            for (int j = 0; j < 5; ++j) z[j] = fmaf(x, W1[t * HID * 5 + f * 5 + j], z[j]);
        }
        float o = b2[t];
#pragma unroll
        for (int j = 0; j < 5; ++j) o = fmaf(fmaxf(z[j], 0.f), W2[t * 5 + j], o);
        vals[t] = o;
    }
    out[g] = vals[0] * oW[0] + vals[1] * oW[1] + ob[0];
}

extern "C" void kernel_launch(void* const* d_in, const int* in_sizes, int n_in,
                              void* d_out, int out_size, void* d_ws, size_t ws_size,
                              hipStream_t stream) {
    const float* x_pe    = (const float*)d_in[0];
    const float* x_r     = (const float*)d_in[1];
    const int* ei_per    = (const int*)d_in[2];
    const int* ei_rpe    = (const int*)d_in[3];
    const int* ei_rr     = (const int*)d_in[4];
    const int* batch_pe  = (const int*)d_in[5];
    const int* batch_r   = (const int*)d_in[6];
    const float* Wrel1   = (const float*)d_in[7];
    const float* brel1   = (const float*)d_in[8];
    const float* Wroot1  = (const float*)d_in[9];
    const float* Wrel23  = (const float*)d_in[10];
    const float* brel23  = (const float*)d_in[11];
    const float* Wroot23 = (const float*)d_in[12];
    const float* mlp_W1  = (const float*)d_in[13];
    const float* mlp_b1  = (const float*)d_in[14];
    const float* mlp_W2  = (const float*)d_in[15];
    const float* mlp_b2  = (const float*)d_in[16];
    const float* out_W   = (const float*)d_in[17];
    const float* out_b   = (const float*)d_in[18];
    float* out = (float*)d_out;

    const int N_PE = in_sizes[0] / DIN;
    const int N_R  = in_sizes[1] / DIN;
    const int E    = in_sizes[2] / 2;
    const int G    = out_size;
    const int NMAX = (N_PE > N_R) ? N_PE : N_R;
    const size_t SZM = (size_t)NMAX * HID;

    // ---- workspace layout ----
    _Float16* H1 = (_Float16*)d_ws;
    _Float16* H2 = H1 + SZM;
    _Float16* H3 = H2 + SZM;
    _Float16* H4 = H3 + SZM;
    _Float16* H5 = H4 + SZM;
    _Float16* xh_pe = H5 + SZM;
    _Float16* xh_r  = xh_pe + (size_t)N_PE * DIN;
    _Float16* wt_rel1    = xh_r + (size_t)N_R * DIN;   // 3 x 128 x 64
    _Float16* wt_root1pe = wt_rel1 + 3 * DIN * HID;    // 128 x 64
    _Float16* wt_wsum1   = wt_root1pe + DIN * HID;     // 128 x 64
    _Float16* wt_rel23   = wt_wsum1 + DIN * HID;       // 6 x 128 x 128
    _Float16* wt_root_l2 = wt_rel23 + 6 * HID * HID;   // 128 x 128 (Wroot23[0][1])
    _Float16* wt_root_l3 = wt_root_l2 + HID * HID;     // 128 x 128 (Wroot23[1][1])
    _Float16* wt_wsum2   = wt_root_l3 + HID * HID;     // 128 x 128
    _Float16* wt_wsum3   = wt_wsum2 + HID * HID;       // 128 x 128
    unsigned* gmU_pe = (unsigned*)(wt_wsum3 + HID * HID);
    unsigned* gmU_r  = gmU_pe + G * HID;
    int* starts_pe = (int*)(gmU_r + G * HID);
    int* starts_r  = starts_pe + (G + 1);
    int* bktCnt = starts_r + (G + 1);            // 3 * NBKMAX
    int* bb     = bktCnt + 3 * NBKMAX;           // 3 * (NBKMAX+1)
    int* gcur   = bb + 3 * (NBKMAX + 1);         // 3 * NBKMAX
    int* csr    = gcur + 3 * NBKMAX;
    const size_t relstride = (size_t)(NMAX + 1) + 2 * (size_t)E + 16;

    int* rp[3]; int* adjp[3]; unsigned* tmp[3];
    const int Nds[3] = {N_R, N_PE, N_R};
    for (int r = 0; r < 3; ++r) {
        int* rowptr = csr + (size_t)r * relstride;
        rp[r] = rowptr;
        adjp[r] = rowptr + (Nds[r] + 1);
        tmp[r] = (unsigned*)(adjp[r] + E);
    }

    const int gpe = (N_PE + 127) / 128, grr = (N_R + 127) / 128;

    // ---- input conversion ----
    {
        int n40 = N_PE * DIN / 4, n41 = N_R * DIN / 4;
        int nmax = n40 > n41 ? n40 : n41;
        dim3 g((nmax + 255) / 256, 2);
        conv_x2_k<<<g, 256, 0, stream>>>(x_pe, xh_pe, n40, x_r, xh_r, n41);
    }
    // ---- weight conversion (+root pre-sums fused), 8 jobs, 1 launch ----
    {
        CW c0{Wrel1, nullptr, wt_rel1, DIN, 3 * DIN * HID};
        CW c1{Wroot1 + 1 * DIN * HID, nullptr, wt_root1pe, DIN, DIN * HID};
        CW c2{Wroot1, Wroot1 + 2 * DIN * HID, wt_wsum1, DIN, DIN * HID};
        CW c3{Wrel23, nullptr, wt_rel23, HID, 6 * HID * HID};
        CW c4{Wroot23 + 1 * HID * HID, nullptr, wt_root_l2, HID, HID * HID};
        CW c5{Wroot23 + 4 * HID * HID, nullptr, wt_root_l3, HID, HID * HID};
        CW c6{Wroot23, Wroot23 + 2 * HID * HID, wt_wsum2, HID, HID * HID};
        CW c7{Wroot23 + 3 * HID * HID, Wroot23 + 5 * HID * HID, wt_wsum3, HID, HID * HID};
        dim3 g((6 * HID * HID + 255) / 256, 8);
        conv_w8_k<<<g, 256, 0, stream>>>(c0, c1, c2, c3, c4, c5, c6, c7);
    }
    // ---- CSR build: bucketed counting sort ----
    {
        hipMemsetAsync(bktCnt, 0, 3 * NBKMAX * sizeof(int), stream);
        int eb = (E + EPB - 1) / EPB;
        dim3 gh(eb, 3);
        bhist_k<<<gh, 256, 0, stream>>>(ei_per, ei_rpe, ei_rr, E,
                                        bktCnt, bktCnt + NBKMAX, bktCnt + 2 * NBKMAX);
        bscan_k<<<1, 256, 0, stream>>>(
            bktCnt, bb, gcur, rp[0], Nds[0],
            bktCnt + NBKMAX, bb + (NBKMAX + 1), gcur + NBKMAX, rp[1], Nds[1],
            bktCnt + 2 * NBKMAX, bb + 2 * (NBKMAX + 1), gcur + 2 * NBKMAX, rp[2], Nds[2], E);
        bin_k<<<gh, 256, 0, stream>>>(ei_per, ei_rpe, ei_rr, E,
                                      gcur, gcur + NBKMAX, gcur + 2 * NBKMAX,
                                      tmp[0], tmp[1], tmp[2]);
        dim3 gc(NBKMAX, 3);
        bcsr_k<<<gc, 256, 0, stream>>>(tmp[0], tmp[1], tmp[2],
                                       bb, bb + (NBKMAX + 1), bb + 2 * (NBKMAX + 1),
                                       rp[0], rp[1], rp[2],
                                       adjp[0], adjp[1], adjp[2],
                                       Nds[0], Nds[1], Nds[2]);
    }

    // ---------- layer 1 (K = 64) ----------
    {
        AJob a0{xh_r, rp[1], adjp[1], H1, N_PE, (N_PE + 31) / 32};
        AJob a1{xh_pe, rp[0], adjp[0], H2, N_R, (N_R + 31) / 32};
        AJob a2{xh_r, rp[2], adjp[2], H3, N_R, (N_R + 31) / 32};
        gather3_k<DIN><<<a0.gb + a1.gb + a2.gb, 256, 0, stream>>>(a0, a1, a2);
        GJob jp{H1, xh_pe, nullptr,
                wt_rel1 + 1 * DIN * HID, wt_root1pe, nullptr,
                brel1 + HID, nullptr, H4, N_PE, 2, gpe};
        GJob jr{H2, H3, xh_r,
                wt_rel1, wt_rel1 + 2 * DIN * HID, wt_wsum1,
                brel1, brel1 + 2 * HID, H5, N_R, 3, grr};
        gemm2_k<true><<<gpe + grr, 256, 0, stream>>>(jp, jr, DIN, 0);
    }
    // ---------- layer 2 (K = 128) ----------
    {
        AJob a0{H5, rp[1], adjp[1], H1, N_PE, (N_PE + 15) / 16};
        AJob a1{H4, rp[0], adjp[0], H2, N_R, (N_R + 15) / 16};
        AJob a2{H5, rp[2], adjp[2], H3, N_R, (N_R + 15) / 16};
        gather3_k<HID><<<a0.gb + a1.gb + a2.gb, 256, 0, stream>>>(a0, a1, a2);
        GJob jp{H1, H4, nullptr,
                wt_rel23 + 1 * HID * HID, wt_root_l2, nullptr,
                brel23 + HID, nullptr, H1, N_PE, 2 * 2, gpe};
        GJob jr{H2, H3, H5,
                wt_rel23, wt_rel23 + 2 * HID * HID, wt_wsum2,
                brel23, brel23 + 2 * HID, H2, N_R, 3 * 2, grr};
        gemm2_k<true><<<gpe + grr, 256, 0, stream>>>(jp, jr, HID, 1);
    }
    // ---------- layer 3 (K = 128), no ReLU ----------
    {
        AJob a0{H2, rp[1], adjp[1], H3, N_PE, (N_PE + 15) / 16};
        AJob a1{H1, rp[0], adjp[0], H4, N_R, (N_R + 15) / 16};
        AJob a2{H2, rp[2], adjp[2], H5, N_R, (N_R + 15) / 16};
        gather3_k<HID><<<a0.gb + a1.gb + a2.gb, 256, 0, stream>>>(a0, a1, a2);
        GJob jp{H3, H1, nullptr,
                wt_rel23 + 4 * HID * HID, wt_root_l3, nullptr,
                brel23 + 4 * HID, nullptr, H3, N_PE, 2 * 2, gpe};
        GJob jr{H4, H5, H2,
                wt_rel23 + 3 * HID * HID, wt_rel23 + 5 * HID * HID, wt_wsum3,
                brel23 + 3 * HID, brel23 + 5 * HID, H4, N_R, 3 * 2, grr};
        gemm2_k<false><<<gpe + grr, 256, 0, stream>>>(jp, jr, HID, 1);
    }

    // ---------- readout ----------
    seg_bounds2_k<<<2, 128, 0, stream>>>(batch_pe, N_PE, starts_pe, batch_r, N_R, starts_r, G);
    hipMemsetAsync(gmU_pe, 0, 2 * (size_t)G * HID * sizeof(unsigned), stream);
    dim3 gs(G, 16, 2);
    seg_max2_k<<<gs, 128, 0, stream>>>(H3, starts_pe, gmU_pe, H4, starts_r, gmU_r);
    head_k<<<1, 64, 0, stream>>>(gmU_pe, gmU_r, mlp_W1, mlp_b1, mlp_W2, mlp_b2, out_W, out_b, out, G);
}

// Round 10
// 619.029 us; speedup vs baseline: 1.2720x; 1.0060x over previous
//
#include <hip/hip_runtime.h>
#include <cstddef>
#include <cstdint>

#define DIN 64
#define HID 128
#define NBKMAX 256   // max dst buckets of 512 nodes -> supports N <= 131072
#define EPB 2048     // edges per bin-pass block

typedef _Float16 half4v __attribute__((ext_vector_type(4)));
typedef _Float16 half8v __attribute__((ext_vector_type(8)));
typedef float f32x16 __attribute__((ext_vector_type(16)));

// ---- order-preserving float<->uint for atomicMax-based segment max ----
__device__ __forceinline__ unsigned encf(float f) {
    unsigned b = __float_as_uint(f);
    return (b & 0x80000000u) ? ~b : (b | 0x80000000u);
}
__device__ __forceinline__ float decf(unsigned u) {
    unsigned b = (u & 0x80000000u) ? (u & 0x7FFFFFFFu) : ~u;
    return __uint_as_float(b);
}

// ---- fp32 -> f16 for both inputs in one launch ----
__global__ void conv_x2_k(const float* s0, _Float16* d0, int n40,
                          const float* s1, _Float16* d1, int n41) {
    int r = blockIdx.y;
    const float* s = r == 0 ? s0 : s1;
    _Float16* d = r == 0 ? d0 : d1;
    int n4 = r == 0 ? n40 : n41;
    int i = blockIdx.x * 256 + threadIdx.x;
    if (i >= n4) return;
    float4 v = *reinterpret_cast<const float4*>(&s[i * 4]);
    half4v h;
    h.x = (_Float16)v.x; h.y = (_Float16)v.y; h.z = (_Float16)v.z; h.w = (_Float16)v.w;
    *reinterpret_cast<half4v*>(&d[i * 4]) = h;
}

// ---- 8 weight convert(+add)+transpose jobs: src [M][K][128] (+src2) -> [M][128][K] f16 ----
struct CW { const float* src; const float* src2; _Float16* dst; int K; int total; };
__global__ void conv_w8_k(CW c0, CW c1, CW c2, CW c3, CW c4, CW c5, CW c6, CW c7) {
    CW J;
    switch (blockIdx.y) {
        case 0: J = c0; break; case 1: J = c1; break; case 2: J = c2; break;
        case 3: J = c3; break; case 4: J = c4; break; case 5: J = c5; break;
        case 6: J = c6; break; default: J = c7; break;
    }
    int i = blockIdx.x * 256 + threadIdx.x;
    if (i >= J.total) return;
    int m = i / (J.K * HID);
    int rem = i % (J.K * HID);
    int k = rem / HID;
    int col = rem % HID;
    float v = J.src[i];
    if (J.src2) v += J.src2[i];
    J.dst[(size_t)m * HID * J.K + (size_t)col * J.K + k] = (_Float16)v;
}

// ================= CSR build via cache-local counting sort =================
__global__ __launch_bounds__(256) void bhist_k(const int* e0, const int* e1, const int* e2, int E,
                                               int* c0, int* c1, int* c2) {
    int r = blockIdx.y;
    const int* ei = r == 0 ? e0 : (r == 1 ? e1 : e2);
    int* cnt = r == 0 ? c0 : (r == 1 ? c1 : c2);
    __shared__ int sc[NBKMAX];
    int t = threadIdx.x;
    sc[t] = 0;
    __syncthreads();
    int base = blockIdx.x * EPB;
    int n = min(EPB, E - base);
    for (int i = t; i < n; i += 256)
        atomicAdd(&sc[(unsigned)ei[E + base + i] >> 9], 1);
    __syncthreads();
    if (sc[t]) atomicAdd(&cnt[t], sc[t]);
}

__global__ __launch_bounds__(256) void bscan_k(int* c0, int* bb0, int* cu0, int* rp0, int n0,
                                               int* c1, int* bb1, int* cu1, int* rp1, int n1,
                                               int* c2, int* bb2, int* cu2, int* rp2, int n2,
                                               int E) {
    __shared__ int sh[256];
    int t = threadIdx.x;
    for (int r = 0; r < 3; ++r) {
        int* cnt = r == 0 ? c0 : (r == 1 ? c1 : c2);
        int* bb  = r == 0 ? bb0 : (r == 1 ? bb1 : bb2);
        int* cu  = r == 0 ? cu0 : (r == 1 ? cu1 : cu2);
        int* rp  = r == 0 ? rp0 : (r == 1 ? rp1 : rp2);
        int N    = r == 0 ? n0 : (r == 1 ? n1 : n2);
        int v = cnt[t];
        sh[t] = v;
        __syncthreads();
        for (int off = 1; off < 256; off <<= 1) {
            int val = (t >= off) ? sh[t - off] : 0;
            __syncthreads();
            sh[t] += val;
            __syncthreads();
        }
        int ex = sh[t] - v;
        bb[t] = ex;
        cu[t] = ex;
        if (t == 255) bb[256] = sh[255];
        if (t == 0) rp[N] = E;
        __syncthreads();
    }
}

__global__ __launch_bounds__(256) void bin_k(const int* e0, const int* e1, const int* e2, int E,
                                             int* cu0, int* cu1, int* cu2,
                                             unsigned* t0, unsigned* t1, unsigned* t2) {
    int r = blockIdx.y;
    const int* ei = r == 0 ? e0 : (r == 1 ? e1 : e2);
    int* gcur = r == 0 ? cu0 : (r == 1 ? cu1 : cu2);
    unsigned* temp = r == 0 ? t0 : (r == 1 ? t1 : t2);
    __shared__ unsigned pk[EPB];
    __shared__ unsigned short bkb[EPB];
    __shared__ int cnt[NBKMAX];
    __shared__ int scn[NBKMAX];
    __shared__ int rb[NBKMAX];
    int t = threadIdx.x;
    int base = blockIdx.x * EPB;
    int n = min(EPB, E - base);
    cnt[t] = 0;
    __syncthreads();
    for (int i = t; i < n; i += 256)
        atomicAdd(&cnt[(unsigned)ei[E + base + i] >> 9], 1);
    __syncthreads();
    {
        int v = cnt[t];
        scn[t] = v;
        __syncthreads();
        for (int off = 1; off < 256; off <<= 1) {
            int val = (t >= off) ? scn[t - off] : 0;
            __syncthreads();
            scn[t] += val;
            __syncthreads();
        }
        int ex = scn[t] - v;
        __syncthreads();
        scn[t] = ex;
    }
    {
        int c = cnt[t];
        rb[t] = c ? atomicAdd(&gcur[t], c) : 0;
        cnt[t] = 0;
    }
    __syncthreads();
    for (int i = t; i < n; i += 256) {
        int s = ei[base + i];
        int d = ei[E + base + i];
        int b = (unsigned)d >> 9;
        int slot = scn[b] + atomicAdd(&cnt[b], 1);
        pk[slot] = ((unsigned)s << 9) | (unsigned)(d & 511);
        bkb[slot] = (unsigned short)b;
    }
    __syncthreads();
    for (int i = t; i < n; i += 256) {
        int b = bkb[i];
        temp[rb[b] + (i - scn[b])] = pk[i];
    }
}

__global__ __launch_bounds__(256) void bcsr_k(const unsigned* t0, const unsigned* t1, const unsigned* t2,
                                              const int* bb0, const int* bb1, const int* bb2,
                                              int* rp0, int* rp1, int* rp2,
                                              int* a0, int* a1, int* a2,
                                              int n0, int n1, int n2) {
    int r = blockIdx.y;
    const unsigned* temp = r == 0 ? t0 : (r == 1 ? t1 : t2);
    const int* bb = r == 0 ? bb0 : (r == 1 ? bb1 : bb2);
    int* rp = r == 0 ? rp0 : (r == 1 ? rp1 : rp2);
    int* adj = r == 0 ? a0 : (r == 1 ? a1 : a2);
    int N = r == 0 ? n0 : (r == 1 ? n1 : n2);
    int b = blockIdx.x;
    int lo = bb[b], hi = bb[b + 1];
    __shared__ int cnt[512];
    __shared__ int sh[256];
    int t = threadIdx.x;
    cnt[t] = 0; cnt[t + 256] = 0;
    __syncthreads();
    for (int i = lo + t; i < hi; i += 256)
        atomicAdd(&cnt[temp[i] & 511], 1);
    __syncthreads();
    int c0 = cnt[2 * t], c1 = cnt[2 * t + 1];
    sh[t] = c0 + c1;
    __syncthreads();
    for (int off = 1; off < 256; off <<= 1) {
        int v = (t >= off) ? sh[t - off] : 0;
        __syncthreads();
        sh[t] += v;
        __syncthreads();
    }
    int pairExcl = sh[t] - (c0 + c1);
    __syncthreads();
    int e0x = lo + pairExcl;
    int e1x = e0x + c0;
    cnt[2 * t] = e0x;
    cnt[2 * t + 1] = e1x;
    int nodeBase = b * 512;
    if (nodeBase + 2 * t < N) rp[nodeBase + 2 * t] = e0x;
    if (nodeBase + 2 * t + 1 < N) rp[nodeBase + 2 * t + 1] = e1x;
    __syncthreads();
    for (int i = lo + t; i < hi; i += 256) {
        unsigned p = temp[i];
        int pos = atomicAdd(&cnt[p & 511], 1);
        adj[pos] = p >> 9;
    }
}

// ---- 3 gather-sum aggregations in one launch ----
// Cooperative adjacency: each of the TPN lanes of a node loads one adj entry per
// 16-edge window; edges broadcast via __shfl -> 1/TPN the adj load instructions.
// X-row loads stay 4-deep independent (node-major, coalesced 256 B rows).
struct AJob { const _Float16* X; const int* rp; const int* adj; _Float16* AGG; int N; int gb; };
template <int D>
__global__ __launch_bounds__(256) void gather3_k(AJob a0, AJob a1, AJob a2) {
    int b = blockIdx.x;
    AJob J;
    if (b < a0.gb) { J = a0; }
    else if (b < a0.gb + a1.gb) { J = a1; b -= a0.gb; }
    else { J = a2; b -= a0.gb + a1.gb; }
    constexpr int TPN = D / 8;
    constexpr int NPB = 256 / TPN;
    int node = b * NPB + threadIdx.x / TPN;
    int glane = threadIdx.x % TPN;
    if (node >= J.N) return;
    int a = J.rp[node], e1 = J.rp[node + 1];
    float acc[8] = {0.f, 0.f, 0.f, 0.f, 0.f, 0.f, 0.f, 0.f};
    for (int base = a; base < e1; base += TPN) {
        int idx = base + glane;
        int myAdj = (idx < e1) ? J.adj[idx] : 0;
        int cnt = min(TPN, e1 - base);
        int j = 0;
        for (; j + 4 <= cnt; j += 4) {
            int s0 = __shfl(myAdj, j, TPN);
            int s1 = __shfl(myAdj, j + 1, TPN);
            int s2 = __shfl(myAdj, j + 2, TPN);
            int s3 = __shfl(myAdj, j + 3, TPN);
            half8v v0 = *reinterpret_cast<const half8v*>(&J.X[(size_t)s0 * D + glane * 8]);
            half8v v1 = *reinterpret_cast<const half8v*>(&J.X[(size_t)s1 * D + glane * 8]);
            half8v v2 = *reinterpret_cast<const half8v*>(&J.X[(size_t)s2 * D + glane * 8]);
            half8v v3 = *reinterpret_cast<const half8v*>(&J.X[(size_t)s3 * D + glane * 8]);
#pragma unroll
            for (int i = 0; i < 8; ++i)
                acc[i] += (float)v0[i] + (float)v1[i] + (float)v2[i] + (float)v3[i];
        }
        for (; j < cnt; ++j) {
            int s0 = __shfl(myAdj, j, TPN);
            half8v v0 = *reinterpret_cast<const half8v*>(&J.X[(size_t)s0 * D + glane * 8]);
#pragma unroll
            for (int i = 0; i < 8; ++i) acc[i] += (float)v0[i];
        }
    }
    half8v o;
#pragma unroll
    for (int i = 0; i < 8; ++i) o[i] = (_Float16)acc[i];
    *reinterpret_cast<half8v*>(&J.AGG[(size_t)node * D + glane * 8]) = o;
}

// ======================= dual-job MFMA GEMM, W staged in LDS =======================
// O[N,128] = sum_s A_s[N,K] @ W_s[K,128] + b0 (+ b1), opt ReLU; f16 act, fp32 acc.
// Epilogue merges lane-pairs (l, l^32 own the same row, interleaved 8 B chunks)
// via shfl_xor -> full 16 B contiguous stores -> no partial-line HBM writes.
struct GJob {
    const _Float16* A0; const _Float16* A1; const _Float16* A2;
    const _Float16* W0; const _Float16* W1; const _Float16* W2;
    const float* b0; const float* b1;
    _Float16* O;
    int N; int total; int gb;   // total = NA * (K/64)
};

template <bool RELU>
__global__ __launch_bounds__(256) void gemm2_k(GJob j0, GJob j1, int K, int lg) {
    const bool second = ((int)blockIdx.x >= j0.gb);
    const GJob J = second ? j1 : j0;
    const int bx = blockIdx.x - (second ? j0.gb : 0);
    __shared__ _Float16 Alds[128 * 64];   // 16 KB
    __shared__ _Float16 Wlds[128 * 64];   // 16 KB
    const int tid = threadIdx.x;
    const int lane = tid & 63;
    const int w = tid >> 6;
    const int wr = w & 1, wc = w >> 1;
    const int rowBase = bx * 128;

    f32x16 acc[2][2];
#pragma unroll
    for (int r = 0; r < 2; ++r)
#pragma unroll
        for (int c = 0; c < 2; ++c)
#pragma unroll
            for (int q = 0; q < 16; ++q) acc[r][c][q] = 0.0f;

    const _Float16* Ap[3] = {J.A0, J.A1, J.A2};

    const int row = tid & 127;
    const int kh = (tid >> 7) * 32;
    const int gr = rowBase + row;
    const bool rowOK = (gr < J.N);
    int offS[4];
#pragma unroll
    for (int j = 0; j < 4; ++j) {
        int t = (kh >> 4) + (j >> 1);
        int k8 = j & 1;
        offS[j] = (((row >> 5) * 4 + t) * 64 + (row & 31) + 32 * k8) * 8;
    }

    const int total = J.total;
    const int cmask = (1 << lg) - 1;

    auto ldA = [&](int c, half8v h[4]) {
        int s = c >> lg;
        int k0 = (c & cmask) * 64;
        half8v z = {};
        h[0] = z; h[1] = z; h[2] = z; h[3] = z;
        if (rowOK) {
            const _Float16* p = Ap[s] + (size_t)gr * K + k0 + kh;
#pragma unroll
            for (int j = 0; j < 4; ++j) h[j] = *reinterpret_cast<const half8v*>(p + j * 8);
        }
    };
    auto ldW = [&](int c, half8v h[4]) {
        int s = c >> lg;
        int k0 = (c & cmask) * 64;
        const _Float16* __restrict__ Wt = (s == 0) ? J.W0 : (s == 1 ? J.W1 : J.W2);
        const _Float16* p = Wt + (size_t)row * K + k0 + kh;   // row == col index here
#pragma unroll
        for (int j = 0; j < 4; ++j) h[j] = *reinterpret_cast<const half8v*>(p + j * 8);
    };

    half8v ra[4], rw[4];
    ldA(0, ra); ldW(0, rw);
#pragma unroll
    for (int j = 0; j < 4; ++j) {
        *reinterpret_cast<half8v*>(&Alds[offS[j]]) = ra[j];
        *reinterpret_cast<half8v*>(&Wlds[offS[j]]) = rw[j];
    }
    __syncthreads();

    for (int c = 0; c < total; ++c) {
        const bool more = (c + 1 < total);
        if (more) { ldA(c + 1, ra); ldW(c + 1, rw); }
#pragma unroll
        for (int t = 0; t < 4; ++t) {
            half8v av[2], wv[2];
#pragma unroll
            for (int r = 0; r < 2; ++r)
                av[r] = *reinterpret_cast<const half8v*>(&Alds[(((wr * 2 + r) * 4 + t) * 64 + lane) * 8]);
#pragma unroll
            for (int cc = 0; cc < 2; ++cc)
                wv[cc] = *reinterpret_cast<const half8v*>(&Wlds[(((wc * 2 + cc) * 4 + t) * 64 + lane) * 8]);
#pragma unroll
            for (int r = 0; r < 2; ++r)
#pragma unroll
                for (int cc = 0; cc < 2; ++cc)
                    acc[r][cc] = __builtin_amdgcn_mfma_f32_32x32x16_f16(wv[cc], av[r], acc[r][cc], 0, 0, 0);
        }
        __syncthreads();
        if (more) {
#pragma unroll
            for (int j = 0; j < 4; ++j) {
                *reinterpret_cast<half8v*>(&Alds[offS[j]]) = ra[j];
                *reinterpret_cast<half8v*>(&Wlds[offS[j]]) = rw[j];
            }
            __syncthreads();
        }
    }

    // ---- epilogue: lane-pair merged 16 B stores ----
    const int half_ = lane >> 5;   // lanes l and l^32 own the same node
#pragma unroll
    for (int r = 0; r < 2; ++r) {
        int node = rowBase + (wr * 2 + r) * 32 + (lane & 31);
        bool ok = (node < J.N);
        _Float16* orow = J.O + (size_t)node * HID;
#pragma unroll
        for (int cc = 0; cc < 2; ++cc) {
            int fbase = wc * 64 + cc * 32;
#pragma unroll
            for (int g = 0; g < 4; ++g) {
                int fmine = fbase + g * 8 + 4 * half_;
                float4 bv = *reinterpret_cast<const float4*>(&J.b0[fmine]);
                if (J.b1) {
                    float4 b2v = *reinterpret_cast<const float4*>(&J.b1[fmine]);
                    bv.x += b2v.x; bv.y += b2v.y; bv.z += b2v.z; bv.w += b2v.w;
                }
                union { half4v h; int i[2]; } m, p;
#pragma unroll
                for (int i = 0; i < 4; ++i) {
                    float v = acc[r][cc][g * 4 + i] + ((const float*)&bv)[i];
                    if (RELU) v = fmaxf(v, 0.f);
                    m.h[i] = (_Float16)v;
                }
                p.i[0] = __shfl_xor(m.i[0], 32);
                p.i[1] = __shfl_xor(m.i[1], 32);
                half4v lo = half_ ? p.h : m.h;
                half4v hi = half_ ? m.h : p.h;
                half8v outv;
#pragma unroll
                for (int i = 0; i < 4; ++i) { outv[i] = lo[i]; outv[4 + i] = hi[i]; }
                if (ok && ((g & 1) == half_))
                    *reinterpret_cast<half8v*>(&orow[fbase + g * 8]) = outv;
            }
        }
    }
}

// ---- segment boundaries for both node types ----
__global__ void seg_bounds2_k(const int* b0, int n0, int* s0,
                              const int* b1, int n1, int* s1, int G) {
    int r = blockIdx.x;
    const int* batch = r == 0 ? b0 : b1;
    int n = r == 0 ? n0 : n1;
    int* starts = r == 0 ? s0 : s1;
    int g = threadIdx.x;
    if (g > G) return;
    int lo = 0, hi = n;
    while (lo < hi) {
        int mid = (lo + hi) >> 1;
        if (batch[mid] < g) lo = mid + 1; else hi = mid;
    }
    starts[g] = lo;
}

// ---- segment max for both node types: grid (G, SUB, 2) ----
__global__ __launch_bounds__(128) void seg_max2_k(const _Float16* H0, const int* st0, unsigned* g0,
                                                  const _Float16* H1, const int* st1, unsigned* g1) {
    int z = blockIdx.z;
    const _Float16* Hf = z == 0 ? H0 : H1;
    const int* starts = z == 0 ? st0 : st1;
    unsigned* gmU = z == 0 ? g0 : g1;
    int g = blockIdx.x;
    int sub = blockIdx.y;
    int SUB = gridDim.y;
    int f = threadIdx.x;
    int s0 = starts[g], s1 = starts[g + 1];
    int len = s1 - s0;
    if (len <= 0) return;
    int chunk = (len + SUB - 1) / SUB;
    int a = s0 + sub * chunk;
    int b = min(a + chunk, s1);
    if (a >= b) return;
    float m = -__builtin_huge_valf();
    for (int n = a; n < b; ++n) m = fmaxf(m, (float)Hf[(size_t)n * HID + f]);
    atomicMax(&gmU[g * HID + f], encf(m));
}

// ---- per-graph MLP heads + final combine ----
__global__ void head_k(const unsigned* __restrict__ gmU_pe, const unsigned* __restrict__ gmU_r,
                       const float* __restrict__ W1, const float* __restrict__ b1,
                       const float* __restrict__ W2, const float* __restrict__ b2,
                       const float* __restrict__ oW, const float* __restrict__ ob,
                       float* __restrict__ out, int G) {
    int g = threadIdx.x;
    if (g >= G) return;
    float vals[2];
#pragma unroll
    for (int t = 0; t < 2; ++t) {
        const unsigned* gm = t ? gmU_r : gmU_pe;
        float z[5];
#pragma unroll
        for (int j = 0; j < 5; ++j) z[j] = b1[t * 5 + j];
        for (int f = 0; f < HID; ++f) {
            float x = decf(gm[g * HID + f]);
#pragma unroll
            for (int j = 0; j < 5; ++j) z[j] = fmaf(x, W1[t * HID * 5 + f * 5 + j], z[j]);
        }
        float o = b2[t];
#pragma unroll
        for (int j = 0; j < 5; ++j) o = fmaf(fmaxf(z[j], 0.f), W2[t * 5 + j], o);
        vals[t] = o;
    }
    out[g] = vals[0] * oW[0] + vals[1] * oW[1] + ob[0];
}

extern "C" void kernel_launch(void* const* d_in, const int* in_sizes, int n_in,
                              void* d_out, int out_size, void* d_ws, size_t ws_size,
                              hipStream_t stream) {
    const float* x_pe    = (const float*)d_in[0];
    const float* x_r     = (const float*)d_in[1];
    const int* ei_per    = (const int*)d_in[2];
    const int* ei_rpe    = (const int*)d_in[3];
    const int* ei_rr     = (const int*)d_in[4];
    const int* batch_pe  = (const int*)d_in[5];
    const int* batch_r   = (const int*)d_in[6];
    const float* Wrel1   = (const float*)d_in[7];
    const float* brel1   = (const float*)d_in[8];
    const float* Wroot1  = (const float*)d_in[9];
    const float* Wrel23  = (const float*)d_in[10];
    const float* brel23  = (const float*)d_in[11];
    const float* Wroot23 = (const float*)d_in[12];
    const float* mlp_W1  = (const float*)d_in[13];
    const float* mlp_b1  = (const float*)d_in[14];
    const float* mlp_W2  = (const float*)d_in[15];
    const float* mlp_b2  = (const float*)d_in[16];
    const float* out_W   = (const float*)d_in[17];
    const float* out_b   = (const float*)d_in[18];
    float* out = (float*)d_out;

    const int N_PE = in_sizes[0] / DIN;
    const int N_R  = in_sizes[1] / DIN;
    const int E    = in_sizes[2] / 2;
    const int G    = out_size;
    const int NMAX = (N_PE > N_R) ? N_PE : N_R;
    const size_t SZM = (size_t)NMAX * HID;

    // ---- workspace layout ----
    _Float16* H1 = (_Float16*)d_ws;
    _Float16* H2 = H1 + SZM;
    _Float16* H3 = H2 + SZM;
    _Float16* H4 = H3 + SZM;
    _Float16* H5 = H4 + SZM;
    _Float16* xh_pe = H5 + SZM;
    _Float16* xh_r  = xh_pe + (size_t)N_PE * DIN;
    _Float16* wt_rel1    = xh_r + (size_t)N_R * DIN;   // 3 x 128 x 64
    _Float16* wt_root1pe = wt_rel1 + 3 * DIN * HID;    // 128 x 64
    _Float16* wt_wsum1   = wt_root1pe + DIN * HID;     // 128 x 64
    _Float16* wt_rel23   = wt_wsum1 + DIN * HID;       // 6 x 128 x 128
    _Float16* wt_root_l2 = wt_rel23 + 6 * HID * HID;   // 128 x 128
    _Float16* wt_root_l3 = wt_root_l2 + HID * HID;     // 128 x 128
    _Float16* wt_wsum2   = wt_root_l3 + HID * HID;     // 128 x 128
    _Float16* wt_wsum3   = wt_wsum2 + HID * HID;       // 128 x 128
    unsigned* gmU_pe = (unsigned*)(wt_wsum3 + HID * HID);
    unsigned* gmU_r  = gmU_pe + G * HID;
    int* starts_pe = (int*)(gmU_r + G * HID);
    int* starts_r  = starts_pe + (G + 1);
    int* bktCnt = starts_r + (G + 1);            // 3 * NBKMAX
    int* bb     = bktCnt + 3 * NBKMAX;           // 3 * (NBKMAX+1)
    int* gcur   = bb + 3 * (NBKMAX + 1);         // 3 * NBKMAX
    int* csr    = gcur + 3 * NBKMAX;
    const size_t relstride = (size_t)(NMAX + 1) + 2 * (size_t)E + 16;

    int* rp[3]; int* adjp[3]; unsigned* tmp[3];
    const int Nds[3] = {N_R, N_PE, N_R};
    for (int r = 0; r < 3; ++r) {
        int* rowptr = csr + (size_t)r * relstride;
        rp[r] = rowptr;
        adjp[r] = rowptr + (Nds[r] + 1);
        tmp[r] = (unsigned*)(adjp[r] + E);
    }

    const int gpe = (N_PE + 127) / 128, grr = (N_R + 127) / 128;

    // ---- input conversion ----
    {
        int n40 = N_PE * DIN / 4, n41 = N_R * DIN / 4;
        int nmax = n40 > n41 ? n40 : n41;
        dim3 g((nmax + 255) / 256, 2);
        conv_x2_k<<<g, 256, 0, stream>>>(x_pe, xh_pe, n40, x_r, xh_r, n41);
    }
    // ---- weight conversion (+root pre-sums fused), 8 jobs ----
    {
        CW c0{Wrel1, nullptr, wt_rel1, DIN, 3 * DIN * HID};
        CW c1{Wroot1 + 1 * DIN * HID, nullptr, wt_root1pe, DIN, DIN * HID};
        CW c2{Wroot1, Wroot1 + 2 * DIN * HID, wt_wsum1, DIN, DIN * HID};
        CW c3{Wrel23, nullptr, wt_rel23, HID, 6 * HID * HID};
        CW c4{Wroot23 + 1 * HID * HID, nullptr, wt_root_l2, HID, HID * HID};
        CW c5{Wroot23 + 4 * HID * HID, nullptr, wt_root_l3, HID, HID * HID};
        CW c6{Wroot23, Wroot23 + 2 * HID * HID, wt_wsum2, HID, HID * HID};
        CW c7{Wroot23 + 3 * HID * HID, Wroot23 + 5 * HID * HID, wt_wsum3, HID, HID * HID};
        dim3 g((6 * HID * HID + 255) / 256, 8);
        conv_w8_k<<<g, 256, 0, stream>>>(c0, c1, c2, c3, c4, c5, c6, c7);
    }
    // ---- CSR build: bucketed counting sort ----
    {
        hipMemsetAsync(bktCnt, 0, 3 * NBKMAX * sizeof(int), stream);
        int eb = (E + EPB - 1) / EPB;
        dim3 gh(eb, 3);
        bhist_k<<<gh, 256, 0, stream>>>(ei_per, ei_rpe, ei_rr, E,
                                        bktCnt, bktCnt + NBKMAX, bktCnt + 2 * NBKMAX);
        bscan_k<<<1, 256, 0, stream>>>(
            bktCnt, bb, gcur, rp[0], Nds[0],
            bktCnt + NBKMAX, bb + (NBKMAX + 1), gcur + NBKMAX, rp[1], Nds[1],
            bktCnt + 2 * NBKMAX, bb + 2 * (NBKMAX + 1), gcur + 2 * NBKMAX, rp[2], Nds[2], E);
        bin_k<<<gh, 256, 0, stream>>>(ei_per, ei_rpe, ei_rr, E,
                                      gcur, gcur + NBKMAX, gcur + 2 * NBKMAX,
                                      tmp[0], tmp[1], tmp[2]);
        dim3 gc(NBKMAX, 3);
        bcsr_k<<<gc, 256, 0, stream>>>(tmp[0], tmp[1], tmp[2],
                                       bb, bb + (NBKMAX + 1), bb + 2 * (NBKMAX + 1),
                                       rp[0], rp[1], rp[2],
                                       adjp[0], adjp[1], adjp[2],
                                       Nds[0], Nds[1], Nds[2]);
    }

    // ---------- layer 1 (K = 64) ----------
    {
        AJob a0{xh_r, rp[1], adjp[1], H1, N_PE, (N_PE + 31) / 32};
        AJob a1{xh_pe, rp[0], adjp[0], H2, N_R, (N_R + 31) / 32};
        AJob a2{xh_r, rp[2], adjp[2], H3, N_R, (N_R + 31) / 32};
        gather3_k<DIN><<<a0.gb + a1.gb + a2.gb, 256, 0, stream>>>(a0, a1, a2);
        GJob jp{H1, xh_pe, nullptr,
                wt_rel1 + 1 * DIN * HID, wt_root1pe, nullptr,
                brel1 + HID, nullptr, H4, N_PE, 2, gpe};
        GJob jr{H2, H3, xh_r,
                wt_rel1, wt_rel1 + 2 * DIN * HID, wt_wsum1,
                brel1, brel1 + 2 * HID, H5, N_R, 3, grr};
        gemm2_k<true><<<gpe + grr, 256, 0, stream>>>(jp, jr, DIN, 0);
    }
    // ---------- layer 2 (K = 128) ----------
    {
        AJob a0{H5, rp[1], adjp[1], H1, N_PE, (N_PE + 15) / 16};
        AJob a1{H4, rp[0], adjp[0], H2, N_R, (N_R + 15) / 16};
        AJob a2{H5, rp[2], adjp[2], H3, N_R, (N_R + 15) / 16};
        gather3_k<HID><<<a0.gb + a1.gb + a2.gb, 256, 0, stream>>>(a0, a1, a2);
        GJob jp{H1, H4, nullptr,
                wt_rel23 + 1 * HID * HID, wt_root_l2, nullptr,
                brel23 + HID, nullptr, H1, N_PE, 2 * 2, gpe};
        GJob jr{H2, H3, H5,
                wt_rel23, wt_rel23 + 2 * HID * HID, wt_wsum2,
                brel23, brel23 + 2 * HID, H2, N_R, 3 * 2, grr};
        gemm2_k<true><<<gpe + grr, 256, 0, stream>>>(jp, jr, HID, 1);
    }
    // ---------- layer 3 (K = 128), no ReLU ----------
    {
        AJob a0{H2, rp[1], adjp[1], H3, N_PE, (N_PE + 15) / 16};
        AJob a1{H1, rp[0], adjp[0], H4, N_R, (N_R + 15) / 16};
        AJob a2{H2, rp[2], adjp[2], H5, N_R, (N_R + 15) / 16};
        gather3_k<HID><<<a0.gb + a1.gb + a2.gb, 256, 0, stream>>>(a0, a1, a2);
        GJob jp{H3, H1, nullptr,
                wt_rel23 + 4 * HID * HID, wt_root_l3, nullptr,
                brel23 + 4 * HID, nullptr, H3, N_PE, 2 * 2, gpe};
        GJob jr{H4, H5, H2,
                wt_rel23 + 3 * HID * HID, wt_rel23 + 5 * HID * HID, wt_wsum3,
                brel23 + 3 * HID, brel23 + 5 * HID, H4, N_R, 3 * 2, grr};
        gemm2_k<false><<<gpe + grr, 256, 0, stream>>>(jp, jr, HID, 1);
    }

    // ---------- readout ----------
    seg_bounds2_k<<<2, 128, 0, stream>>>(batch_pe, N_PE, starts_pe, batch_r, N_R, starts_r, G);
    hipMemsetAsync(gmU_pe, 0, 2 * (size_t)G * HID * sizeof(unsigned), stream);
    dim3 gs(G, 16, 2);
    seg_max2_k<<<gs, 128, 0, stream>>>(H3, starts_pe, gmU_pe, H4, starts_r, gmU_r);
    head_k<<<1, 64, 0, stream>>>(gmU_pe, gmU_r, mlp_W1, mlp_b1, mlp_W2, mlp_b2, out_W, out_b, out, G);
}

// Round 11
// 611.346 us; speedup vs baseline: 1.2880x; 1.0126x over previous
//
#include <hip/hip_runtime.h>
#include <cstddef>
#include <cstdint>

#define DIN 64
#define HID 128
#define NBKMAX 256   // max dst buckets of 512 nodes -> supports N <= 131072
#define EPB 2048     // edges per bin-pass block

typedef _Float16 half4v __attribute__((ext_vector_type(4)));
typedef _Float16 half8v __attribute__((ext_vector_type(8)));
typedef float f32x16 __attribute__((ext_vector_type(16)));

// ---- order-preserving float<->uint for atomicMax-based segment max ----
__device__ __forceinline__ unsigned encf(float f) {
    unsigned b = __float_as_uint(f);
    return (b & 0x80000000u) ? ~b : (b | 0x80000000u);
}
__device__ __forceinline__ float decf(unsigned u) {
    unsigned b = (u & 0x80000000u) ? (u & 0x7FFFFFFFu) : ~u;
    return __uint_as_float(b);
}

// ---- fp32 -> f16 for both inputs in one launch ----
__global__ void conv_x2_k(const float* s0, _Float16* d0, int n40,
                          const float* s1, _Float16* d1, int n41) {
    int r = blockIdx.y;
    const float* s = r == 0 ? s0 : s1;
    _Float16* d = r == 0 ? d0 : d1;
    int n4 = r == 0 ? n40 : n41;
    int i = blockIdx.x * 256 + threadIdx.x;
    if (i >= n4) return;
    float4 v = *reinterpret_cast<const float4*>(&s[i * 4]);
    half4v h;
    h.x = (_Float16)v.x; h.y = (_Float16)v.y; h.z = (_Float16)v.z; h.w = (_Float16)v.w;
    *reinterpret_cast<half4v*>(&d[i * 4]) = h;
}

// ---- prep mega-kernel: 8 weight convert(+add)+transpose jobs (y=0..7),
//      bucket histogram x3 relations (y=8..10), segment bounds (y=11) ----
struct CW { const float* src; const float* src2; _Float16* dst; int K; int total; };
__global__ __launch_bounds__(256) void prep_k(
    CW c0, CW c1, CW c2, CW c3, CW c4, CW c5, CW c6, CW c7,
    const int* e0, const int* e1, const int* e2, int E,
    int* hc0, int* hc1, int* hc2,
    const int* bpe, int npe, int* spe,
    const int* brr, int nrr, int* srr, int G) {
    int y = blockIdx.y;
    if (y < 8) {
        CW J;
        switch (y) {
            case 0: J = c0; break; case 1: J = c1; break; case 2: J = c2; break;
            case 3: J = c3; break; case 4: J = c4; break; case 5: J = c5; break;
            case 6: J = c6; break; default: J = c7; break;
        }
        int i = blockIdx.x * 256 + threadIdx.x;
        if (i >= J.total) return;
        int m = i / (J.K * HID);
        int rem = i % (J.K * HID);
        int k = rem / HID;
        int col = rem % HID;
        float v = J.src[i];
        if (J.src2) v += J.src2[i];
        J.dst[(size_t)m * HID * J.K + (size_t)col * J.K + k] = (_Float16)v;
    } else if (y < 11) {
        int r = y - 8;
        const int* ei = r == 0 ? e0 : (r == 1 ? e1 : e2);
        int* cnt = r == 0 ? hc0 : (r == 1 ? hc1 : hc2);
        __shared__ int sc[NBKMAX];
        int t = threadIdx.x;
        sc[t] = 0;
        __syncthreads();
        int base = blockIdx.x * EPB;
        if (base >= E) return;
        int n = min(EPB, E - base);
        for (int i = t; i < n; i += 256)
            atomicAdd(&sc[(unsigned)ei[E + base + i] >> 9], 1);
        __syncthreads();
        if (sc[t]) atomicAdd(&cnt[t], sc[t]);
    } else {
        int r = blockIdx.x;
        if (r >= 2) return;
        const int* batch = r == 0 ? bpe : brr;
        int n = r == 0 ? npe : nrr;
        int* starts = r == 0 ? spe : srr;
        int g = threadIdx.x;
        if (g > G) return;
        int lo = 0, hi = n;
        while (lo < hi) {
            int mid = (lo + hi) >> 1;
            if (batch[mid] < g) lo = mid + 1; else hi = mid;
        }
        starts[g] = lo;
    }
}

// ================= CSR build via cache-local counting sort =================
__global__ __launch_bounds__(256) void bscan_k(int* c0, int* bb0, int* cu0, int* rp0, int n0,
                                               int* c1, int* bb1, int* cu1, int* rp1, int n1,
                                               int* c2, int* bb2, int* cu2, int* rp2, int n2,
                                               int E) {
    __shared__ int sh[256];
    int t = threadIdx.x;
    for (int r = 0; r < 3; ++r) {
        int* cnt = r == 0 ? c0 : (r == 1 ? c1 : c2);
        int* bb  = r == 0 ? bb0 : (r == 1 ? bb1 : bb2);
        int* cu  = r == 0 ? cu0 : (r == 1 ? cu1 : cu2);
        int* rp  = r == 0 ? rp0 : (r == 1 ? rp1 : rp2);
        int N    = r == 0 ? n0 : (r == 1 ? n1 : n2);
        int v = cnt[t];
        sh[t] = v;
        __syncthreads();
        for (int off = 1; off < 256; off <<= 1) {
            int val = (t >= off) ? sh[t - off] : 0;
            __syncthreads();
            sh[t] += val;
            __syncthreads();
        }
        int ex = sh[t] - v;
        bb[t] = ex;
        cu[t] = ex;
        if (t == 255) bb[256] = sh[255];
        if (t == 0) rp[N] = E;
        __syncthreads();
    }
}

__global__ __launch_bounds__(256) void bin_k(const int* e0, const int* e1, const int* e2, int E,
                                             int* cu0, int* cu1, int* cu2,
                                             unsigned* t0, unsigned* t1, unsigned* t2) {
    int r = blockIdx.y;
    const int* ei = r == 0 ? e0 : (r == 1 ? e1 : e2);
    int* gcur = r == 0 ? cu0 : (r == 1 ? cu1 : cu2);
    unsigned* temp = r == 0 ? t0 : (r == 1 ? t1 : t2);
    __shared__ unsigned pk[EPB];
    __shared__ unsigned short bkb[EPB];
    __shared__ int cnt[NBKMAX];
    __shared__ int scn[NBKMAX];
    __shared__ int rb[NBKMAX];
    int t = threadIdx.x;
    int base = blockIdx.x * EPB;
    int n = min(EPB, E - base);
    cnt[t] = 0;
    __syncthreads();
    for (int i = t; i < n; i += 256)
        atomicAdd(&cnt[(unsigned)ei[E + base + i] >> 9], 1);
    __syncthreads();
    {
        int v = cnt[t];
        scn[t] = v;
        __syncthreads();
        for (int off = 1; off < 256; off <<= 1) {
            int val = (t >= off) ? scn[t - off] : 0;
            __syncthreads();
            scn[t] += val;
            __syncthreads();
        }
        int ex = scn[t] - v;
        __syncthreads();
        scn[t] = ex;
    }
    {
        int c = cnt[t];
        rb[t] = c ? atomicAdd(&gcur[t], c) : 0;
        cnt[t] = 0;
    }
    __syncthreads();
    for (int i = t; i < n; i += 256) {
        int s = ei[base + i];
        int d = ei[E + base + i];
        int b = (unsigned)d >> 9;
        int slot = scn[b] + atomicAdd(&cnt[b], 1);
        pk[slot] = ((unsigned)s << 9) | (unsigned)(d & 511);
        bkb[slot] = (unsigned short)b;
    }
    __syncthreads();
    for (int i = t; i < n; i += 256) {
        int b = bkb[i];
        temp[rb[b] + (i - scn[b])] = pk[i];
    }
}

__global__ __launch_bounds__(256) void bcsr_k(const unsigned* t0, const unsigned* t1, const unsigned* t2,
                                              const int* bb0, const int* bb1, const int* bb2,
                                              int* rp0, int* rp1, int* rp2,
                                              int* a0, int* a1, int* a2,
                                              int n0, int n1, int n2) {
    int r = blockIdx.y;
    const unsigned* temp = r == 0 ? t0 : (r == 1 ? t1 : t2);
    const int* bb = r == 0 ? bb0 : (r == 1 ? bb1 : bb2);
    int* rp = r == 0 ? rp0 : (r == 1 ? rp1 : rp2);
    int* adj = r == 0 ? a0 : (r == 1 ? a1 : a2);
    int N = r == 0 ? n0 : (r == 1 ? n1 : n2);
    int b = blockIdx.x;
    int lo = bb[b], hi = bb[b + 1];
    __shared__ int cnt[512];
    __shared__ int sh[256];
    int t = threadIdx.x;
    cnt[t] = 0; cnt[t + 256] = 0;
    __syncthreads();
    for (int i = lo + t; i < hi; i += 256)
        atomicAdd(&cnt[temp[i] & 511], 1);
    __syncthreads();
    int c0 = cnt[2 * t], c1 = cnt[2 * t + 1];
    sh[t] = c0 + c1;
    __syncthreads();
    for (int off = 1; off < 256; off <<= 1) {
        int v = (t >= off) ? sh[t - off] : 0;
        __syncthreads();
        sh[t] += v;
        __syncthreads();
    }
    int pairExcl = sh[t] - (c0 + c1);
    __syncthreads();
    int e0x = lo + pairExcl;
    int e1x = e0x + c0;
    cnt[2 * t] = e0x;
    cnt[2 * t + 1] = e1x;
    int nodeBase = b * 512;
    if (nodeBase + 2 * t < N) rp[nodeBase + 2 * t] = e0x;
    if (nodeBase + 2 * t + 1 < N) rp[nodeBase + 2 * t + 1] = e1x;
    __syncthreads();
    for (int i = lo + t; i < hi; i += 256) {
        unsigned p = temp[i];
        int pos = atomicAdd(&cnt[p & 511], 1);
        adj[pos] = p >> 9;
    }
}

// ---- 3 gather-sum aggregations in one launch (cooperative adj via shfl) ----
struct AJob { const _Float16* X; const int* rp; const int* adj; _Float16* AGG; int N; int gb; };
template <int D>
__global__ __launch_bounds__(256) void gather3_k(AJob a0, AJob a1, AJob a2) {
    int b = blockIdx.x;
    AJob J;
    if (b < a0.gb) { J = a0; }
    else if (b < a0.gb + a1.gb) { J = a1; b -= a0.gb; }
    else { J = a2; b -= a0.gb + a1.gb; }
    constexpr int TPN = D / 8;
    constexpr int NPB = 256 / TPN;
    int node = b * NPB + threadIdx.x / TPN;
    int glane = threadIdx.x % TPN;
    if (node >= J.N) return;
    int a = J.rp[node], e1 = J.rp[node + 1];
    float acc[8] = {0.f, 0.f, 0.f, 0.f, 0.f, 0.f, 0.f, 0.f};
    for (int base = a; base < e1; base += TPN) {
        int idx = base + glane;
        int myAdj = (idx < e1) ? J.adj[idx] : 0;
        int cnt = min(TPN, e1 - base);
        int j = 0;
        for (; j + 4 <= cnt; j += 4) {
            int s0 = __shfl(myAdj, j, TPN);
            int s1 = __shfl(myAdj, j + 1, TPN);
            int s2 = __shfl(myAdj, j + 2, TPN);
            int s3 = __shfl(myAdj, j + 3, TPN);
            half8v v0 = *reinterpret_cast<const half8v*>(&J.X[(size_t)s0 * D + glane * 8]);
            half8v v1 = *reinterpret_cast<const half8v*>(&J.X[(size_t)s1 * D + glane * 8]);
            half8v v2 = *reinterpret_cast<const half8v*>(&J.X[(size_t)s2 * D + glane * 8]);
            half8v v3 = *reinterpret_cast<const half8v*>(&J.X[(size_t)s3 * D + glane * 8]);
#pragma unroll
            for (int i = 0; i < 8; ++i)
                acc[i] += (float)v0[i] + (float)v1[i] + (float)v2[i] + (float)v3[i];
        }
        for (; j < cnt; ++j) {
            int s0 = __shfl(myAdj, j, TPN);
            half8v v0 = *reinterpret_cast<const half8v*>(&J.X[(size_t)s0 * D + glane * 8]);
#pragma unroll
            for (int i = 0; i < 8; ++i) acc[i] += (float)v0[i];
        }
    }
    half8v o;
#pragma unroll
    for (int i = 0; i < 8; ++i) o[i] = (_Float16)acc[i];
    *reinterpret_cast<half8v*>(&J.AGG[(size_t)node * D + glane * 8]) = o;
}

// ======================= dual-job MFMA GEMM, 512 threads =======================
// O[N,128] = sum_s A_s[N,K] @ W_s[K,128] + b0 (+ b1), opt ReLU; f16 act, fp32 acc.
// 128x128 tile, 8 waves: each wave a 64-row x 32-col slab (2 C-tiles, 32 acc
// VGPRs) -> more resident waves + shorter inter-barrier chains for the
// latency-bound profile. A and W both staged in frag-ready LDS (32 KB).
// Epilogue lane-pair merge -> full 16 B contiguous stores.
// In-place O==A_s is safe: each block reads only the rows it writes.
struct GJob {
    const _Float16* A0; const _Float16* A1; const _Float16* A2;
    const _Float16* W0; const _Float16* W1; const _Float16* W2;
    const float* b0; const float* b1;
    _Float16* O;
    int N; int total; int gb;   // total = NA * (K/64)
};

template <bool RELU>
__global__ __launch_bounds__(512) void gemm2_k(GJob j0, GJob j1, int K, int lg) {
    const bool second = ((int)blockIdx.x >= j0.gb);
    const GJob J = second ? j1 : j0;
    const int bx = blockIdx.x - (second ? j0.gb : 0);
    __shared__ _Float16 Alds[128 * 64];   // 16 KB
    __shared__ _Float16 Wlds[128 * 64];   // 16 KB
    const int tid = threadIdx.x;
    const int lane = tid & 63;
    const int w = tid >> 6;          // 8 waves
    const int wr = w & 1;            // 64-row half
    const int wc = w >> 1;           // 32-col quarter (0..3)
    const int rowBase = bx * 128;

    f32x16 acc[2];
#pragma unroll
    for (int r = 0; r < 2; ++r)
#pragma unroll
        for (int q = 0; q < 16; ++q) acc[r][q] = 0.0f;

    const _Float16* Ap[3] = {J.A0, J.A1, J.A2};

    // staging: thread -> (row/col = tid&127, k-quarter = (tid>>7)*16 halves);
    // 2x16 B loads per thread; frag region R = (idx>>5)*4 + t, slot (idx&31)+32*k8.
    const int row = tid & 127;
    const int kq = (tid >> 7) * 16;   // k offset in halves: 0,16,32,48
    const int gr = rowBase + row;
    const bool rowOK = (gr < J.N);
    int offS[2];
#pragma unroll
    for (int j = 0; j < 2; ++j)
        offS[j] = (((row >> 5) * 4 + (kq >> 4)) * 64 + (row & 31) + 32 * j) * 8;

    const int total = J.total;
    const int cmask = (1 << lg) - 1;

    auto ldA = [&](int c, half8v h[2]) {
        int s = c >> lg;
        int k0 = (c & cmask) * 64;
        half8v z = {};
        h[0] = z; h[1] = z;
        if (rowOK) {
            const _Float16* p = Ap[s] + (size_t)gr * K + k0 + kq;
            h[0] = *reinterpret_cast<const half8v*>(p);
            h[1] = *reinterpret_cast<const half8v*>(p + 8);
        }
    };
    auto ldW = [&](int c, half8v h[2]) {
        int s = c >> lg;
        int k0 = (c & cmask) * 64;
        const _Float16* __restrict__ Wt = (s == 0) ? J.W0 : (s == 1 ? J.W1 : J.W2);
        const _Float16* p = Wt + (size_t)row * K + k0 + kq;   // row == col index
        h[0] = *reinterpret_cast<const half8v*>(p);
        h[1] = *reinterpret_cast<const half8v*>(p + 8);
    };

    half8v ra[2], rw[2];
    ldA(0, ra); ldW(0, rw);
#pragma unroll
    for (int j = 0; j < 2; ++j) {
        *reinterpret_cast<half8v*>(&Alds[offS[j]]) = ra[j];
        *reinterpret_cast<half8v*>(&Wlds[offS[j]]) = rw[j];
    }
    __syncthreads();

    for (int c = 0; c < total; ++c) {
        const bool more = (c + 1 < total);
        if (more) { ldA(c + 1, ra); ldW(c + 1, rw); }
#pragma unroll
        for (int t = 0; t < 4; ++t) {
            half8v wv = *reinterpret_cast<const half8v*>(&Wlds[((wc * 4 + t) * 64 + lane) * 8]);
#pragma unroll
            for (int r = 0; r < 2; ++r) {
                half8v av = *reinterpret_cast<const half8v*>(
                    &Alds[(((wr * 2 + r) * 4 + t) * 64 + lane) * 8]);
                acc[r] = __builtin_amdgcn_mfma_f32_32x32x16_f16(wv, av, acc[r], 0, 0, 0);
            }
        }
        __syncthreads();
        if (more) {
#pragma unroll
            for (int j = 0; j < 2; ++j) {
                *reinterpret_cast<half8v*>(&Alds[offS[j]]) = ra[j];
                *reinterpret_cast<half8v*>(&Wlds[offS[j]]) = rw[j];
            }
            __syncthreads();
        }
    }

    // ---- epilogue: lane-pair merged 16 B stores ----
    const int half_ = lane >> 5;   // lanes l and l^32 own the same node
    const int fbase = wc * 32;
#pragma unroll
    for (int r = 0; r < 2; ++r) {
        int node = rowBase + (wr * 2 + r) * 32 + (lane & 31);
        bool ok = (node < J.N);
        _Float16* orow = J.O + (size_t)node * HID;
#pragma unroll
        for (int g = 0; g < 4; ++g) {
            int fmine = fbase + g * 8 + 4 * half_;
            float4 bv = *reinterpret_cast<const float4*>(&J.b0[fmine]);
            if (J.b1) {
                float4 b2v = *reinterpret_cast<const float4*>(&J.b1[fmine]);
                bv.x += b2v.x; bv.y += b2v.y; bv.z += b2v.z; bv.w += b2v.w;
            }
            union { half4v h; int i[2]; } m, p;
#pragma unroll
            for (int i = 0; i < 4; ++i) {
                float v = acc[r][g * 4 + i] + ((const float*)&bv)[i];
                if (RELU) v = fmaxf(v, 0.f);
                m.h[i] = (_Float16)v;
            }
            p.i[0] = __shfl_xor(m.i[0], 32);
            p.i[1] = __shfl_xor(m.i[1], 32);
            half4v lo = half_ ? p.h : m.h;
            half4v hi = half_ ? m.h : p.h;
            half8v outv;
#pragma unroll
            for (int i = 0; i < 4; ++i) { outv[i] = lo[i]; outv[4 + i] = hi[i]; }
            if (ok && ((g & 1) == half_))
                *reinterpret_cast<half8v*>(&orow[fbase + g * 8]) = outv;
        }
    }
}

// ---- segment max for both node types: grid (G, SUB, 2) ----
__global__ __launch_bounds__(128) void seg_max2_k(const _Float16* H0, const int* st0, unsigned* g0,
                                                  const _Float16* H1, const int* st1, unsigned* g1) {
    int z = blockIdx.z;
    const _Float16* Hf = z == 0 ? H0 : H1;
    const int* starts = z == 0 ? st0 : st1;
    unsigned* gmU = z == 0 ? g0 : g1;
    int g = blockIdx.x;
    int sub = blockIdx.y;
    int SUB = gridDim.y;
    int f = threadIdx.x;
    int s0 = starts[g], s1 = starts[g + 1];
    int len = s1 - s0;
    if (len <= 0) return;
    int chunk = (len + SUB - 1) / SUB;
    int a = s0 + sub * chunk;
    int b = min(a + chunk, s1);
    if (a >= b) return;
    float m = -__builtin_huge_valf();
    for (int n = a; n < b; ++n) m = fmaxf(m, (float)Hf[(size_t)n * HID + f]);
    atomicMax(&gmU[g * HID + f], encf(m));
}

// ---- per-graph MLP heads + final combine ----
__global__ void head_k(const unsigned* __restrict__ gmU_pe, const unsigned* __restrict__ gmU_r,
                       const float* __restrict__ W1, const float* __restrict__ b1,
                       const float* __restrict__ W2, const float* __restrict__ b2,
                       const float* __restrict__ oW, const float* __restrict__ ob,
                       float* __restrict__ out, int G) {
    int g = threadIdx.x;
    if (g >= G) return;
    float vals[2];
#pragma unroll
    for (int t = 0; t < 2; ++t) {
        const unsigned* gm = t ? gmU_r : gmU_pe;
        float z[5];
#pragma unroll
        for (int j = 0; j < 5; ++j) z[j] = b1[t * 5 + j];
        for (int f = 0; f < HID; ++f) {
            float x = decf(gm[g * HID + f]);
#pragma unroll
            for (int j = 0; j < 5; ++j) z[j] = fmaf(x, W1[t * HID * 5 + f * 5 + j], z[j]);
        }
        float o = b2[t];
#pragma unroll
        for (int j = 0; j < 5; ++j) o = fmaf(fmaxf(z[j], 0.f), W2[t * 5 + j], o);
        vals[t] = o;
    }
    out[g] = vals[0] * oW[0] + vals[1] * oW[1] + ob[0];
}

extern "C" void kernel_launch(void* const* d_in, const int* in_sizes, int n_in,
                              void* d_out, int out_size, void* d_ws, size_t ws_size,
                              hipStream_t stream) {
    const float* x_pe    = (const float*)d_in[0];
    const float* x_r     = (const float*)d_in[1];
    const int* ei_per    = (const int*)d_in[2];
    const int* ei_rpe    = (const int*)d_in[3];
    const int* ei_rr     = (const int*)d_in[4];
    const int* batch_pe  = (const int*)d_in[5];
    const int* batch_r   = (const int*)d_in[6];
    const float* Wrel1   = (const float*)d_in[7];
    const float* brel1   = (const float*)d_in[8];
    const float* Wroot1  = (const float*)d_in[9];
    const float* Wrel23  = (const float*)d_in[10];
    const float* brel23  = (const float*)d_in[11];
    const float* Wroot23 = (const float*)d_in[12];
    const float* mlp_W1  = (const float*)d_in[13];
    const float* mlp_b1  = (const float*)d_in[14];
    const float* mlp_W2  = (const float*)d_in[15];
    const float* mlp_b2  = (const float*)d_in[16];
    const float* out_W   = (const float*)d_in[17];
    const float* out_b   = (const float*)d_in[18];
    float* out = (float*)d_out;

    const int N_PE = in_sizes[0] / DIN;
    const int N_R  = in_sizes[1] / DIN;
    const int E    = in_sizes[2] / 2;
    const int G    = out_size;
    const int NMAX = (N_PE > N_R) ? N_PE : N_R;
    const size_t SZM = (size_t)NMAX * HID;

    // ---- workspace layout ----
    _Float16* H1 = (_Float16*)d_ws;
    _Float16* H2 = H1 + SZM;
    _Float16* H3 = H2 + SZM;
    _Float16* H4 = H3 + SZM;
    _Float16* H5 = H4 + SZM;
    _Float16* xh_pe = H5 + SZM;
    _Float16* xh_r  = xh_pe + (size_t)N_PE * DIN;
    _Float16* wt_rel1    = xh_r + (size_t)N_R * DIN;   // 3 x 128 x 64
    _Float16* wt_root1pe = wt_rel1 + 3 * DIN * HID;    // 128 x 64
    _Float16* wt_wsum1   = wt_root1pe + DIN * HID;     // 128 x 64
    _Float16* wt_rel23   = wt_wsum1 + DIN * HID;       // 6 x 128 x 128
    _Float16* wt_root_l2 = wt_rel23 + 6 * HID * HID;   // 128 x 128
    _Float16* wt_root_l3 = wt_root_l2 + HID * HID;     // 128 x 128
    _Float16* wt_wsum2   = wt_root_l3 + HID * HID;     // 128 x 128
    _Float16* wt_wsum3   = wt_wsum2 + HID * HID;       // 128 x 128
    // gmU and bktCnt contiguous -> one memset covers both
    unsigned* gmU_pe = (unsigned*)(wt_wsum3 + HID * HID);
    unsigned* gmU_r  = gmU_pe + G * HID;
    int* bktCnt = (int*)(gmU_r + G * HID);       // 3 * NBKMAX
    int* starts_pe = bktCnt + 3 * NBKMAX;
    int* starts_r  = starts_pe + (G + 1);
    int* bb     = starts_r + (G + 1);            // 3 * (NBKMAX+1)
    int* gcur   = bb + 3 * (NBKMAX + 1);         // 3 * NBKMAX
    int* csr    = gcur + 3 * NBKMAX;
    const size_t relstride = (size_t)(NMAX + 1) + 2 * (size_t)E + 16;

    int* rp[3]; int* adjp[3]; unsigned* tmp[3];
    const int Nds[3] = {N_R, N_PE, N_R};
    for (int r = 0; r < 3; ++r) {
        int* rowptr = csr + (size_t)r * relstride;
        rp[r] = rowptr;
        adjp[r] = rowptr + (Nds[r] + 1);
        tmp[r] = (unsigned*)(adjp[r] + E);
    }

    const int gpe = (N_PE + 127) / 128, grr = (N_R + 127) / 128;
    const int eb = (E + EPB - 1) / EPB;

    // ---- zero gmU + bucket counters (contiguous) ----
    hipMemsetAsync(gmU_pe, 0, (2 * (size_t)G * HID + 3 * NBKMAX) * sizeof(int), stream);
    // ---- input conversion ----
    {
        int n40 = N_PE * DIN / 4, n41 = N_R * DIN / 4;
        int nmax = n40 > n41 ? n40 : n41;
        dim3 g((nmax + 255) / 256, 2);
        conv_x2_k<<<g, 256, 0, stream>>>(x_pe, xh_pe, n40, x_r, xh_r, n41);
    }
    // ---- prep: weight conversion + bucket hist + segment bounds, 1 launch ----
    {
        CW c0{Wrel1, nullptr, wt_rel1, DIN, 3 * DIN * HID};
        CW c1{Wroot1 + 1 * DIN * HID, nullptr, wt_root1pe, DIN, DIN * HID};
        CW c2{Wroot1, Wroot1 + 2 * DIN * HID, wt_wsum1, DIN, DIN * HID};
        CW c3{Wrel23, nullptr, wt_rel23, HID, 6 * HID * HID};
        CW c4{Wroot23 + 1 * HID * HID, nullptr, wt_root_l2, HID, HID * HID};
        CW c5{Wroot23 + 4 * HID * HID, nullptr, wt_root_l3, HID, HID * HID};
        CW c6{Wroot23, Wroot23 + 2 * HID * HID, wt_wsum2, HID, HID * HID};
        CW c7{Wroot23 + 3 * HID * HID, Wroot23 + 5 * HID * HID, wt_wsum3, HID, HID * HID};
        int gx = (6 * HID * HID + 255) / 256;
        if (eb > gx) gx = eb;
        dim3 g(gx, 12);
        prep_k<<<g, 256, 0, stream>>>(c0, c1, c2, c3, c4, c5, c6, c7,
                                      ei_per, ei_rpe, ei_rr, E,
                                      bktCnt, bktCnt + NBKMAX, bktCnt + 2 * NBKMAX,
                                      batch_pe, N_PE, starts_pe,
                                      batch_r, N_R, starts_r, G);
    }
    // ---- CSR build ----
    {
        bscan_k<<<1, 256, 0, stream>>>(
            bktCnt, bb, gcur, rp[0], Nds[0],
            bktCnt + NBKMAX, bb + (NBKMAX + 1), gcur + NBKMAX, rp[1], Nds[1],
            bktCnt + 2 * NBKMAX, bb + 2 * (NBKMAX + 1), gcur + 2 * NBKMAX, rp[2], Nds[2], E);
        dim3 gh(eb, 3);
        bin_k<<<gh, 256, 0, stream>>>(ei_per, ei_rpe, ei_rr, E,
                                      gcur, gcur + NBKMAX, gcur + 2 * NBKMAX,
                                      tmp[0], tmp[1], tmp[2]);
        dim3 gc(NBKMAX, 3);
        bcsr_k<<<gc, 256, 0, stream>>>(tmp[0], tmp[1], tmp[2],
                                       bb, bb + (NBKMAX + 1), bb + 2 * (NBKMAX + 1),
                                       rp[0], rp[1], rp[2],
                                       adjp[0], adjp[1], adjp[2],
                                       Nds[0], Nds[1], Nds[2]);
    }

    // ---------- layer 1 (K = 64) ----------
    {
        AJob a0{xh_r, rp[1], adjp[1], H1, N_PE, (N_PE + 31) / 32};
        AJob a1{xh_pe, rp[0], adjp[0], H2, N_R, (N_R + 31) / 32};
        AJob a2{xh_r, rp[2], adjp[2], H3, N_R, (N_R + 31) / 32};
        gather3_k<DIN><<<a0.gb + a1.gb + a2.gb, 256, 0, stream>>>(a0, a1, a2);
        GJob jp{H1, xh_pe, nullptr,
                wt_rel1 + 1 * DIN * HID, wt_root1pe, nullptr,
                brel1 + HID, nullptr, H4, N_PE, 2, gpe};
        GJob jr{H2, H3, xh_r,
                wt_rel1, wt_rel1 + 2 * DIN * HID, wt_wsum1,
                brel1, brel1 + 2 * HID, H5, N_R, 3, grr};
        gemm2_k<true><<<gpe + grr, 512, 0, stream>>>(jp, jr, DIN, 0);
    }
    // ---------- layer 2 (K = 128) ----------
    {
        AJob a0{H5, rp[1], adjp[1], H1, N_PE, (N_PE + 15) / 16};
        AJob a1{H4, rp[0], adjp[0], H2, N_R, (N_R + 15) / 16};
        AJob a2{H5, rp[2], adjp[2], H3, N_R, (N_R + 15) / 16};
        gather3_k<HID><<<a0.gb + a1.gb + a2.gb, 256, 0, stream>>>(a0, a1, a2);
        GJob jp{H1, H4, nullptr,
                wt_rel23 + 1 * HID * HID, wt_root_l2, nullptr,
                brel23 + HID, nullptr, H1, N_PE, 2 * 2, gpe};
        GJob jr{H2, H3, H5,
                wt_rel23, wt_rel23 + 2 * HID * HID, wt_wsum2,
                brel23, brel23 + 2 * HID, H2, N_R, 3 * 2, grr};
        gemm2_k<true><<<gpe + grr, 512, 0, stream>>>(jp, jr, HID, 1);
    }
    // ---------- layer 3 (K = 128), no ReLU ----------
    {
        AJob a0{H2, rp[1], adjp[1], H3, N_PE, (N_PE + 15) / 16};
        AJob a1{H1, rp[0], adjp[0], H4, N_R, (N_R + 15) / 16};
        AJob a2{H2, rp[2], adjp[2], H5, N_R, (N_R + 15) / 16};
        gather3_k<HID><<<a0.gb + a1.gb + a2.gb, 256, 0, stream>>>(a0, a1, a2);
        GJob jp{H3, H1, nullptr,
                wt_rel23 + 4 * HID * HID, wt_root_l3, nullptr,
                brel23 + 4 * HID, nullptr, H3, N_PE, 2 * 2, gpe};
        GJob jr{H4, H5, H2,
                wt_rel23 + 3 * HID * HID, wt_rel23 + 5 * HID * HID, wt_wsum3,
                brel23 + 3 * HID, brel23 + 5 * HID, H4, N_R, 3 * 2, grr};
        gemm2_k<false><<<gpe + grr, 512, 0, stream>>>(jp, jr, HID, 1);
    }

    // ---------- readout ----------
    dim3 gs(G, 16, 2);
    seg_max2_k<<<gs, 128, 0, stream>>>(H3, starts_pe, gmU_pe, H4, starts_r, gmU_r);
    head_k<<<1, 64, 0, stream>>>(gmU_pe, gmU_r, mlp_W1, mlp_b1, mlp_W2, mlp_b2, out_W, out_b, out, G);
}

// Round 12
// 592.823 us; speedup vs baseline: 1.3282x; 1.0312x over previous
//
#include <hip/hip_runtime.h>
#include <cstddef>
#include <cstdint>

#define DIN 64
#define HID 128
#define NBKMAX 256   // max dst buckets of 512 nodes -> supports N <= 131072
#define EPB 2048     // edges per bin-pass block

typedef _Float16 half4v __attribute__((ext_vector_type(4)));
typedef _Float16 half8v __attribute__((ext_vector_type(8)));
typedef float f32x16 __attribute__((ext_vector_type(16)));

// ---- order-preserving float<->uint for atomicMax-based segment max ----
__device__ __forceinline__ unsigned encf(float f) {
    unsigned b = __float_as_uint(f);
    return (b & 0x80000000u) ? ~b : (b | 0x80000000u);
}
__device__ __forceinline__ float decf(unsigned u) {
    unsigned b = (u & 0x80000000u) ? (u & 0x7FFFFFFFu) : ~u;
    return __uint_as_float(b);
}

// ---- fp32 -> f16 for both inputs in one launch ----
__global__ void conv_x2_k(const float* s0, _Float16* d0, int n40,
                          const float* s1, _Float16* d1, int n41) {
    int r = blockIdx.y;
    const float* s = r == 0 ? s0 : s1;
    _Float16* d = r == 0 ? d0 : d1;
    int n4 = r == 0 ? n40 : n41;
    int i = blockIdx.x * 256 + threadIdx.x;
    if (i >= n4) return;
    float4 v = *reinterpret_cast<const float4*>(&s[i * 4]);
    half4v h;
    h.x = (_Float16)v.x; h.y = (_Float16)v.y; h.z = (_Float16)v.z; h.w = (_Float16)v.w;
    *reinterpret_cast<half4v*>(&d[i * 4]) = h;
}

// ---- prep mega-kernel: 8 weight convert(+add)+transpose jobs (y=0..7),
//      bucket histogram x3 relations (y=8..10), segment bounds (y=11) ----
struct CW { const float* src; const float* src2; _Float16* dst; int K; int total; };
__global__ __launch_bounds__(256) void prep_k(
    CW c0, CW c1, CW c2, CW c3, CW c4, CW c5, CW c6, CW c7,
    const int* e0, const int* e1, const int* e2, int E,
    int* hc0, int* hc1, int* hc2,
    const int* bpe, int npe, int* spe,
    const int* brr, int nrr, int* srr, int G) {
    int y = blockIdx.y;
    if (y < 8) {
        CW J;
        switch (y) {
            case 0: J = c0; break; case 1: J = c1; break; case 2: J = c2; break;
            case 3: J = c3; break; case 4: J = c4; break; case 5: J = c5; break;
            case 6: J = c6; break; default: J = c7; break;
        }
        int i = blockIdx.x * 256 + threadIdx.x;
        if (i >= J.total) return;
        int m = i / (J.K * HID);
        int rem = i % (J.K * HID);
        int k = rem / HID;
        int col = rem % HID;
        float v = J.src[i];
        if (J.src2) v += J.src2[i];
        J.dst[(size_t)m * HID * J.K + (size_t)col * J.K + k] = (_Float16)v;
    } else if (y < 11) {
        int r = y - 8;
        const int* ei = r == 0 ? e0 : (r == 1 ? e1 : e2);
        int* cnt = r == 0 ? hc0 : (r == 1 ? hc1 : hc2);
        __shared__ int sc[NBKMAX];
        int t = threadIdx.x;
        sc[t] = 0;
        __syncthreads();
        int base = blockIdx.x * EPB;
        if (base >= E) return;
        int n = min(EPB, E - base);
        for (int i = t; i < n; i += 256)
            atomicAdd(&sc[(unsigned)ei[E + base + i] >> 9], 1);
        __syncthreads();
        if (sc[t]) atomicAdd(&cnt[t], sc[t]);
    } else {
        int r = blockIdx.x;
        if (r >= 2) return;
        const int* batch = r == 0 ? bpe : brr;
        int n = r == 0 ? npe : nrr;
        int* starts = r == 0 ? spe : srr;
        int g = threadIdx.x;
        if (g > G) return;
        int lo = 0, hi = n;
        while (lo < hi) {
            int mid = (lo + hi) >> 1;
            if (batch[mid] < g) lo = mid + 1; else hi = mid;
        }
        starts[g] = lo;
    }
}

// ================= CSR build via cache-local counting sort =================
__global__ __launch_bounds__(256) void bscan_k(int* c0, int* bb0, int* cu0, int* rp0, int n0,
                                               int* c1, int* bb1, int* cu1, int* rp1, int n1,
                                               int* c2, int* bb2, int* cu2, int* rp2, int n2,
                                               int E) {
    __shared__ int sh[256];
    int t = threadIdx.x;
    for (int r = 0; r < 3; ++r) {
        int* cnt = r == 0 ? c0 : (r == 1 ? c1 : c2);
        int* bb  = r == 0 ? bb0 : (r == 1 ? bb1 : bb2);
        int* cu  = r == 0 ? cu0 : (r == 1 ? cu1 : cu2);
        int* rp  = r == 0 ? rp0 : (r == 1 ? rp1 : rp2);
        int N    = r == 0 ? n0 : (r == 1 ? n1 : n2);
        int v = cnt[t];
        sh[t] = v;
        __syncthreads();
        for (int off = 1; off < 256; off <<= 1) {
            int val = (t >= off) ? sh[t - off] : 0;
            __syncthreads();
            sh[t] += val;
            __syncthreads();
        }
        int ex = sh[t] - v;
        bb[t] = ex;
        cu[t] = ex;
        if (t == 255) bb[256] = sh[255];
        if (t == 0) rp[N] = E;
        __syncthreads();
    }
}

__global__ __launch_bounds__(256) void bin_k(const int* e0, const int* e1, const int* e2, int E,
                                             int* cu0, int* cu1, int* cu2,
                                             unsigned* t0, unsigned* t1, unsigned* t2) {
    int r = blockIdx.y;
    const int* ei = r == 0 ? e0 : (r == 1 ? e1 : e2);
    int* gcur = r == 0 ? cu0 : (r == 1 ? cu1 : cu2);
    unsigned* temp = r == 0 ? t0 : (r == 1 ? t1 : t2);
    __shared__ unsigned pk[EPB];
    __shared__ unsigned short bkb[EPB];
    __shared__ int cnt[NBKMAX];
    __shared__ int scn[NBKMAX];
    __shared__ int rb[NBKMAX];
    int t = threadIdx.x;
    int base = blockIdx.x * EPB;
    int n = min(EPB, E - base);
    cnt[t] = 0;
    __syncthreads();
    for (int i = t; i < n; i += 256)
        atomicAdd(&cnt[(unsigned)ei[E + base + i] >> 9], 1);
    __syncthreads();
    {
        int v = cnt[t];
        scn[t] = v;
        __syncthreads();
        for (int off = 1; off < 256; off <<= 1) {
            int val = (t >= off) ? scn[t - off] : 0;
            __syncthreads();
            scn[t] += val;
            __syncthreads();
        }
        int ex = scn[t] - v;
        __syncthreads();
        scn[t] = ex;
    }
    {
        int c = cnt[t];
        rb[t] = c ? atomicAdd(&gcur[t], c) : 0;
        cnt[t] = 0;
    }
    __syncthreads();
    for (int i = t; i < n; i += 256) {
        int s = ei[base + i];
        int d = ei[E + base + i];
        int b = (unsigned)d >> 9;
        int slot = scn[b] + atomicAdd(&cnt[b], 1);
        pk[slot] = ((unsigned)s << 9) | (unsigned)(d & 511);
        bkb[slot] = (unsigned short)b;
    }
    __syncthreads();
    for (int i = t; i < n; i += 256) {
        int b = bkb[i];
        temp[rb[b] + (i - scn[b])] = pk[i];
    }
}

__global__ __launch_bounds__(256) void bcsr_k(const unsigned* t0, const unsigned* t1, const unsigned* t2,
                                              const int* bb0, const int* bb1, const int* bb2,
                                              int* rp0, int* rp1, int* rp2,
                                              int* a0, int* a1, int* a2,
                                              int n0, int n1, int n2) {
    int r = blockIdx.y;
    const unsigned* temp = r == 0 ? t0 : (r == 1 ? t1 : t2);
    const int* bb = r == 0 ? bb0 : (r == 1 ? bb1 : bb2);
    int* rp = r == 0 ? rp0 : (r == 1 ? rp1 : rp2);
    int* adj = r == 0 ? a0 : (r == 1 ? a1 : a2);
    int N = r == 0 ? n0 : (r == 1 ? n1 : n2);
    int b = blockIdx.x;
    int lo = bb[b], hi = bb[b + 1];
    __shared__ int cnt[512];
    __shared__ int sh[256];
    int t = threadIdx.x;
    cnt[t] = 0; cnt[t + 256] = 0;
    __syncthreads();
    for (int i = lo + t; i < hi; i += 256)
        atomicAdd(&cnt[temp[i] & 511], 1);
    __syncthreads();
    int c0 = cnt[2 * t], c1 = cnt[2 * t + 1];
    sh[t] = c0 + c1;
    __syncthreads();
    for (int off = 1; off < 256; off <<= 1) {
        int v = (t >= off) ? sh[t - off] : 0;
        __syncthreads();
        sh[t] += v;
        __syncthreads();
    }
    int pairExcl = sh[t] - (c0 + c1);
    __syncthreads();
    int e0x = lo + pairExcl;
    int e1x = e0x + c0;
    cnt[2 * t] = e0x;
    cnt[2 * t + 1] = e1x;
    int nodeBase = b * 512;
    if (nodeBase + 2 * t < N) rp[nodeBase + 2 * t] = e0x;
    if (nodeBase + 2 * t + 1 < N) rp[nodeBase + 2 * t + 1] = e1x;
    __syncthreads();
    for (int i = lo + t; i < hi; i += 256) {
        unsigned p = temp[i];
        int pos = atomicAdd(&cnt[p & 511], 1);
        adj[pos] = p >> 9;
    }
}

// ---- 3 gather-sum aggregations in one launch (cooperative adj via shfl) ----
struct AJob { const _Float16* X; const int* rp; const int* adj; _Float16* AGG; int N; int gb; };
template <int D>
__global__ __launch_bounds__(256) void gather3_k(AJob a0, AJob a1, AJob a2) {
    int b = blockIdx.x;
    AJob J;
    if (b < a0.gb) { J = a0; }
    else if (b < a0.gb + a1.gb) { J = a1; b -= a0.gb; }
    else { J = a2; b -= a0.gb + a1.gb; }
    constexpr int TPN = D / 8;
    constexpr int NPB = 256 / TPN;
    int node = b * NPB + threadIdx.x / TPN;
    int glane = threadIdx.x % TPN;
    if (node >= J.N) return;
    int a = J.rp[node], e1 = J.rp[node + 1];
    float acc[8] = {0.f, 0.f, 0.f, 0.f, 0.f, 0.f, 0.f, 0.f};
    for (int base = a; base < e1; base += TPN) {
        int idx = base + glane;
        int myAdj = (idx < e1) ? J.adj[idx] : 0;
        int cnt = min(TPN, e1 - base);
        int j = 0;
        for (; j + 4 <= cnt; j += 4) {
            int s0 = __shfl(myAdj, j, TPN);
            int s1 = __shfl(myAdj, j + 1, TPN);
            int s2 = __shfl(myAdj, j + 2, TPN);
            int s3 = __shfl(myAdj, j + 3, TPN);
            half8v v0 = *reinterpret_cast<const half8v*>(&J.X[(size_t)s0 * D + glane * 8]);
            half8v v1 = *reinterpret_cast<const half8v*>(&J.X[(size_t)s1 * D + glane * 8]);
            half8v v2 = *reinterpret_cast<const half8v*>(&J.X[(size_t)s2 * D + glane * 8]);
            half8v v3 = *reinterpret_cast<const half8v*>(&J.X[(size_t)s3 * D + glane * 8]);
#pragma unroll
            for (int i = 0; i < 8; ++i)
                acc[i] += (float)v0[i] + (float)v1[i] + (float)v2[i] + (float)v3[i];
        }
        for (; j < cnt; ++j) {
            int s0 = __shfl(myAdj, j, TPN);
            half8v v0 = *reinterpret_cast<const half8v*>(&J.X[(size_t)s0 * D + glane * 8]);
#pragma unroll
            for (int i = 0; i < 8; ++i) acc[i] += (float)v0[i];
        }
    }
    half8v o;
#pragma unroll
    for (int i = 0; i < 8; ++i) o[i] = (_Float16)acc[i];
    *reinterpret_cast<half8v*>(&J.AGG[(size_t)node * D + glane * 8]) = o;
}

// ======================= dual-job MFMA GEMM, 256 threads, W in LDS =======================
// Round-10 shape (proven best point on the cache-capacity curve): 128x128 tile,
// 4 waves, each wave 64x64 (4 C-tiles); A and W staged frag-ready in LDS (32 KB,
// single-buffered, 1-chunk register prefetch); lane-pair merged 16 B stores.
// In-place O==A_s is safe: each block reads only the rows it writes.
struct GJob {
    const _Float16* A0; const _Float16* A1; const _Float16* A2;
    const _Float16* W0; const _Float16* W1; const _Float16* W2;
    const float* b0; const float* b1;
    _Float16* O;
    int N; int total; int gb;   // total = NA * (K/64)
};

template <bool RELU>
__global__ __launch_bounds__(256) void gemm2_k(GJob j0, GJob j1, int K, int lg) {
    const bool second = ((int)blockIdx.x >= j0.gb);
    const GJob J = second ? j1 : j0;
    const int bx = blockIdx.x - (second ? j0.gb : 0);
    __shared__ _Float16 Alds[128 * 64];   // 16 KB
    __shared__ _Float16 Wlds[128 * 64];   // 16 KB
    const int tid = threadIdx.x;
    const int lane = tid & 63;
    const int w = tid >> 6;
    const int wr = w & 1, wc = w >> 1;
    const int rowBase = bx * 128;

    f32x16 acc[2][2];
#pragma unroll
    for (int r = 0; r < 2; ++r)
#pragma unroll
        for (int c = 0; c < 2; ++c)
#pragma unroll
            for (int q = 0; q < 16; ++q) acc[r][c][q] = 0.0f;

    const _Float16* Ap[3] = {J.A0, J.A1, J.A2};

    const int row = tid & 127;
    const int kh = (tid >> 7) * 32;
    const int gr = rowBase + row;
    const bool rowOK = (gr < J.N);
    int offS[4];
#pragma unroll
    for (int j = 0; j < 4; ++j) {
        int t = (kh >> 4) + (j >> 1);
        int k8 = j & 1;
        offS[j] = (((row >> 5) * 4 + t) * 64 + (row & 31) + 32 * k8) * 8;
    }

    const int total = J.total;
    const int cmask = (1 << lg) - 1;

    auto ldA = [&](int c, half8v h[4]) {
        int s = c >> lg;
        int k0 = (c & cmask) * 64;
        half8v z = {};
        h[0] = z; h[1] = z; h[2] = z; h[3] = z;
        if (rowOK) {
            const _Float16* p = Ap[s] + (size_t)gr * K + k0 + kh;
#pragma unroll
            for (int j = 0; j < 4; ++j) h[j] = *reinterpret_cast<const half8v*>(p + j * 8);
        }
    };
    auto ldW = [&](int c, half8v h[4]) {
        int s = c >> lg;
        int k0 = (c & cmask) * 64;
        const _Float16* __restrict__ Wt = (s == 0) ? J.W0 : (s == 1 ? J.W1 : J.W2);
        const _Float16* p = Wt + (size_t)row * K + k0 + kh;   // row == col index here
#pragma unroll
        for (int j = 0; j < 4; ++j) h[j] = *reinterpret_cast<const half8v*>(p + j * 8);
    };

    half8v ra[4], rw[4];
    ldA(0, ra); ldW(0, rw);
#pragma unroll
    for (int j = 0; j < 4; ++j) {
        *reinterpret_cast<half8v*>(&Alds[offS[j]]) = ra[j];
        *reinterpret_cast<half8v*>(&Wlds[offS[j]]) = rw[j];
    }
    __syncthreads();

    for (int c = 0; c < total; ++c) {
        const bool more = (c + 1 < total);
        if (more) { ldA(c + 1, ra); ldW(c + 1, rw); }
#pragma unroll
        for (int t = 0; t < 4; ++t) {
            half8v av[2], wv[2];
#pragma unroll
            for (int r = 0; r < 2; ++r)
                av[r] = *reinterpret_cast<const half8v*>(&Alds[(((wr * 2 + r) * 4 + t) * 64 + lane) * 8]);
#pragma unroll
            for (int cc = 0; cc < 2; ++cc)
                wv[cc] = *reinterpret_cast<const half8v*>(&Wlds[(((wc * 2 + cc) * 4 + t) * 64 + lane) * 8]);
#pragma unroll
            for (int r = 0; r < 2; ++r)
#pragma unroll
                for (int cc = 0; cc < 2; ++cc)
                    acc[r][cc] = __builtin_amdgcn_mfma_f32_32x32x16_f16(wv[cc], av[r], acc[r][cc], 0, 0, 0);
        }
        __syncthreads();
        if (more) {
#pragma unroll
            for (int j = 0; j < 4; ++j) {
                *reinterpret_cast<half8v*>(&Alds[offS[j]]) = ra[j];
                *reinterpret_cast<half8v*>(&Wlds[offS[j]]) = rw[j];
            }
            __syncthreads();
        }
    }

    // ---- epilogue: lane-pair merged 16 B stores ----
    const int half_ = lane >> 5;   // lanes l and l^32 own the same node
#pragma unroll
    for (int r = 0; r < 2; ++r) {
        int node = rowBase + (wr * 2 + r) * 32 + (lane & 31);
        bool ok = (node < J.N);
        _Float16* orow = J.O + (size_t)node * HID;
#pragma unroll
        for (int cc = 0; cc < 2; ++cc) {
            int fbase = wc * 64 + cc * 32;
#pragma unroll
            for (int g = 0; g < 4; ++g) {
                int fmine = fbase + g * 8 + 4 * half_;
                float4 bv = *reinterpret_cast<const float4*>(&J.b0[fmine]);
                if (J.b1) {
                    float4 b2v = *reinterpret_cast<const float4*>(&J.b1[fmine]);
                    bv.x += b2v.x; bv.y += b2v.y; bv.z += b2v.z; bv.w += b2v.w;
                }
                union { half4v h; int i[2]; } m, p;
#pragma unroll
                for (int i = 0; i < 4; ++i) {
                    float v = acc[r][cc][g * 4 + i] + ((const float*)&bv)[i];
                    if (RELU) v = fmaxf(v, 0.f);
                    m.h[i] = (_Float16)v;
                }
                p.i[0] = __shfl_xor(m.i[0], 32);
                p.i[1] = __shfl_xor(m.i[1], 32);
                half4v lo = half_ ? p.h : m.h;
                half4v hi = half_ ? m.h : p.h;
                half8v outv;
#pragma unroll
                for (int i = 0; i < 4; ++i) { outv[i] = lo[i]; outv[4 + i] = hi[i]; }
                if (ok && ((g & 1) == half_))
                    *reinterpret_cast<half8v*>(&orow[fbase + g * 8]) = outv;
            }
        }
    }
}

// ---- segment max for both node types: grid (G, SUB, 2) ----
__global__ __launch_bounds__(128) void seg_max2_k(const _Float16* H0, const int* st0, unsigned* g0,
                                                  const _Float16* H1, const int* st1, unsigned* g1) {
    int z = blockIdx.z;
    const _Float16* Hf = z == 0 ? H0 : H1;
    const int* starts = z == 0 ? st0 : st1;
    unsigned* gmU = z == 0 ? g0 : g1;
    int g = blockIdx.x;
    int sub = blockIdx.y;
    int SUB = gridDim.y;
    int f = threadIdx.x;
    int s0 = starts[g], s1 = starts[g + 1];
    int len = s1 - s0;
    if (len <= 0) return;
    int chunk = (len + SUB - 1) / SUB;
    int a = s0 + sub * chunk;
    int b = min(a + chunk, s1);
    if (a >= b) return;
    float m = -__builtin_huge_valf();
    for (int n = a; n < b; ++n) m = fmaxf(m, (float)Hf[(size_t)n * HID + f]);
    atomicMax(&gmU[g * HID + f], encf(m));
}

// ---- per-graph MLP heads + final combine ----
__global__ void head_k(const unsigned* __restrict__ gmU_pe, const unsigned* __restrict__ gmU_r,
                       const float* __restrict__ W1, const float* __restrict__ b1,
                       const float* __restrict__ W2, const float* __restrict__ b2,
                       const float* __restrict__ oW, const float* __restrict__ ob,
                       float* __restrict__ out, int G) {
    int g = threadIdx.x;
    if (g >= G) return;
    float vals[2];
#pragma unroll
    for (int t = 0; t < 2; ++t) {
        const unsigned* gm = t ? gmU_r : gmU_pe;
        float z[5];
#pragma unroll
        for (int j = 0; j < 5; ++j) z[j] = b1[t * 5 + j];
        for (int f = 0; f < HID; ++f) {
            float x = decf(gm[g * HID + f]);
#pragma unroll
            for (int j = 0; j < 5; ++j) z[j] = fmaf(x, W1[t * HID * 5 + f * 5 + j], z[j]);
        }
        float o = b2[t];
#pragma unroll
        for (int j = 0; j < 5; ++j) o = fmaf(fmaxf(z[j], 0.f), W2[t * 5 + j], o);
        vals[t] = o;
    }
    out[g] = vals[0] * oW[0] + vals[1] * oW[1] + ob[0];
}

extern "C" void kernel_launch(void* const* d_in, const int* in_sizes, int n_in,
                              void* d_out, int out_size, void* d_ws, size_t ws_size,
                              hipStream_t stream) {
    const float* x_pe    = (const float*)d_in[0];
    const float* x_r     = (const float*)d_in[1];
    const int* ei_per    = (const int*)d_in[2];
    const int* ei_rpe    = (const int*)d_in[3];
    const int* ei_rr     = (const int*)d_in[4];
    const int* batch_pe  = (const int*)d_in[5];
    const int* batch_r   = (const int*)d_in[6];
    const float* Wrel1   = (const float*)d_in[7];
    const float* brel1   = (const float*)d_in[8];
    const float* Wroot1  = (const float*)d_in[9];
    const float* Wrel23  = (const float*)d_in[10];
    const float* brel23  = (const float*)d_in[11];
    const float* Wroot23 = (const float*)d_in[12];
    const float* mlp_W1  = (const float*)d_in[13];
    const float* mlp_b1  = (const float*)d_in[14];
    const float* mlp_W2  = (const float*)d_in[15];
    const float* mlp_b2  = (const float*)d_in[16];
    const float* out_W   = (const float*)d_in[17];
    const float* out_b   = (const float*)d_in[18];
    float* out = (float*)d_out;

    const int N_PE = in_sizes[0] / DIN;
    const int N_R  = in_sizes[1] / DIN;
    const int E    = in_sizes[2] / 2;
    const int G    = out_size;
    const int NMAX = (N_PE > N_R) ? N_PE : N_R;
    const size_t SZM = (size_t)NMAX * HID;

    // ---- workspace layout ----
    _Float16* H1 = (_Float16*)d_ws;
    _Float16* H2 = H1 + SZM;
    _Float16* H3 = H2 + SZM;
    _Float16* H4 = H3 + SZM;
    _Float16* H5 = H4 + SZM;
    _Float16* xh_pe = H5 + SZM;
    _Float16* xh_r  = xh_pe + (size_t)N_PE * DIN;
    _Float16* wt_rel1    = xh_r + (size_t)N_R * DIN;   // 3 x 128 x 64
    _Float16* wt_root1pe = wt_rel1 + 3 * DIN * HID;    // 128 x 64
    _Float16* wt_wsum1   = wt_root1pe + DIN * HID;     // 128 x 64
    _Float16* wt_rel23   = wt_wsum1 + DIN * HID;       // 6 x 128 x 128
    _Float16* wt_root_l2 = wt_rel23 + 6 * HID * HID;   // 128 x 128
    _Float16* wt_root_l3 = wt_root_l2 + HID * HID;     // 128 x 128
    _Float16* wt_wsum2   = wt_root_l3 + HID * HID;     // 128 x 128
    _Float16* wt_wsum3   = wt_wsum2 + HID * HID;       // 128 x 128
    unsigned* gmU_pe = (unsigned*)(wt_wsum3 + HID * HID);
    unsigned* gmU_r  = gmU_pe + G * HID;
    int* bktCnt = (int*)(gmU_r + G * HID);       // 3 * NBKMAX
    int* starts_pe = bktCnt + 3 * NBKMAX;
    int* starts_r  = starts_pe + (G + 1);
    int* bb     = starts_r + (G + 1);            // 3 * (NBKMAX+1)
    int* gcur   = bb + 3 * (NBKMAX + 1);         // 3 * NBKMAX
    int* csr    = gcur + 3 * NBKMAX;
    const size_t relstride = (size_t)(NMAX + 1) + 2 * (size_t)E + 16;

    int* rp[3]; int* adjp[3]; unsigned* tmp[3];
    const int Nds[3] = {N_R, N_PE, N_R};
    for (int r = 0; r < 3; ++r) {
        int* rowptr = csr + (size_t)r * relstride;
        rp[r] = rowptr;
        adjp[r] = rowptr + (Nds[r] + 1);
        tmp[r] = (unsigned*)(adjp[r] + E);
    }

    const int gpe = (N_PE + 127) / 128, grr = (N_R + 127) / 128;
    const int eb = (E + EPB - 1) / EPB;

    // ---- zero gmU + bucket counters (contiguous) ----
    hipMemsetAsync(gmU_pe, 0, (2 * (size_t)G * HID + 3 * NBKMAX) * sizeof(int), stream);
    // ---- input conversion ----
    {
        int n40 = N_PE * DIN / 4, n41 = N_R * DIN / 4;
        int nmax = n40 > n41 ? n40 : n41;
        dim3 g((nmax + 255) / 256, 2);
        conv_x2_k<<<g, 256, 0, stream>>>(x_pe, xh_pe, n40, x_r, xh_r, n41);
    }
    // ---- prep: weight conversion + bucket hist + segment bounds, 1 launch ----
    {
        CW c0{Wrel1, nullptr, wt_rel1, DIN, 3 * DIN * HID};
        CW c1{Wroot1 + 1 * DIN * HID, nullptr, wt_root1pe, DIN, DIN * HID};
        CW c2{Wroot1, Wroot1 + 2 * DIN * HID, wt_wsum1, DIN, DIN * HID};
        CW c3{Wrel23, nullptr, wt_rel23, HID, 6 * HID * HID};
        CW c4{Wroot23 + 1 * HID * HID, nullptr, wt_root_l2, HID, HID * HID};
        CW c5{Wroot23 + 4 * HID * HID, nullptr, wt_root_l3, HID, HID * HID};
        CW c6{Wroot23, Wroot23 + 2 * HID * HID, wt_wsum2, HID, HID * HID};
        CW c7{Wroot23 + 3 * HID * HID, Wroot23 + 5 * HID * HID, wt_wsum3, HID, HID * HID};
        int gx = (6 * HID * HID + 255) / 256;
        if (eb > gx) gx = eb;
        dim3 g(gx, 12);
        prep_k<<<g, 256, 0, stream>>>(c0, c1, c2, c3, c4, c5, c6, c7,
                                      ei_per, ei_rpe, ei_rr, E,
                                      bktCnt, bktCnt + NBKMAX, bktCnt + 2 * NBKMAX,
                                      batch_pe, N_PE, starts_pe,
                                      batch_r, N_R, starts_r, G);
    }
    // ---- CSR build ----
    {
        bscan_k<<<1, 256, 0, stream>>>(
            bktCnt, bb, gcur, rp[0], Nds[0],
            bktCnt + NBKMAX, bb + (NBKMAX + 1), gcur + NBKMAX, rp[1], Nds[1],
            bktCnt + 2 * NBKMAX, bb + 2 * (NBKMAX + 1), gcur + 2 * NBKMAX, rp[2], Nds[2], E);
        dim3 gh(eb, 3);
        bin_k<<<gh, 256, 0, stream>>>(ei_per, ei_rpe, ei_rr, E,
                                      gcur, gcur + NBKMAX, gcur + 2 * NBKMAX,
                                      tmp[0], tmp[1], tmp[2]);
        dim3 gc(NBKMAX, 3);
        bcsr_k<<<gc, 256, 0, stream>>>(tmp[0], tmp[1], tmp[2],
                                       bb, bb + (NBKMAX + 1), bb + 2 * (NBKMAX + 1),
                                       rp[0], rp[1], rp[2],
                                       adjp[0], adjp[1], adjp[2],
                                       Nds[0], Nds[1], Nds[2]);
    }

    // ---------- layer 1 (K = 64) ----------
    {
        AJob a0{xh_r, rp[1], adjp[1], H1, N_PE, (N_PE + 31) / 32};
        AJob a1{xh_pe, rp[0], adjp[0], H2, N_R, (N_R + 31) / 32};
        AJob a2{xh_r, rp[2], adjp[2], H3, N_R, (N_R + 31) / 32};
        gather3_k<DIN><<<a0.gb + a1.gb + a2.gb, 256, 0, stream>>>(a0, a1, a2);
        GJob jp{H1, xh_pe, nullptr,
                wt_rel1 + 1 * DIN * HID, wt_root1pe, nullptr,
                brel1 + HID, nullptr, H4, N_PE, 2, gpe};
        GJob jr{H2, H3, xh_r,
                wt_rel1, wt_rel1 + 2 * DIN * HID, wt_wsum1,
                brel1, brel1 + 2 * HID, H5, N_R, 3, grr};
        gemm2_k<true><<<gpe + grr, 256, 0, stream>>>(jp, jr, DIN, 0);
    }
    // ---------- layer 2 (K = 128) ----------
    {
        AJob a0{H5, rp[1], adjp[1], H1, N_PE, (N_PE + 15) / 16};
        AJob a1{H4, rp[0], adjp[0], H2, N_R, (N_R + 15) / 16};
        AJob a2{H5, rp[2], adjp[2], H3, N_R, (N_R + 15) / 16};
        gather3_k<HID><<<a0.gb + a1.gb + a2.gb, 256, 0, stream>>>(a0, a1, a2);
        GJob jp{H1, H4, nullptr,
                wt_rel23 + 1 * HID * HID, wt_root_l2, nullptr,
                brel23 + HID, nullptr, H1, N_PE, 2 * 2, gpe};
        GJob jr{H2, H3, H5,
                wt_rel23, wt_rel23 + 2 * HID * HID, wt_wsum2,
                brel23, brel23 + 2 * HID, H2, N_R, 3 * 2, grr};
        gemm2_k<true><<<gpe + grr, 256, 0, stream>>>(jp, jr, HID, 1);
    }
    // ---------- layer 3 (K = 128), no ReLU ----------
    {
        AJob a0{H2, rp[1], adjp[1], H3, N_PE, (N_PE + 15) / 16};
        AJob a1{H1, rp[0], adjp[0], H4, N_R, (N_R + 15) / 16};
        AJob a2{H2, rp[2], adjp[2], H5, N_R, (N_R + 15) / 16};
        gather3_k<HID><<<a0.gb + a1.gb + a2.gb, 256, 0, stream>>>(a0, a1, a2);
        GJob jp{H3, H1, nullptr,
                wt_rel23 + 4 * HID * HID, wt_root_l3, nullptr,
                brel23 + 4 * HID, nullptr, H3, N_PE, 2 * 2, gpe};
        GJob jr{H4, H5, H2,
                wt_rel23 + 3 * HID * HID, wt_rel23 + 5 * HID * HID, wt_wsum3,
                brel23 + 3 * HID, brel23 + 5 * HID, H4, N_R, 3 * 2, grr};
        gemm2_k<false><<<gpe + grr, 256, 0, stream>>>(jp, jr, HID, 1);
    }

    // ---------- readout ----------
    dim3 gs(G, 16, 2);
    seg_max2_k<<<gs, 128, 0, stream>>>(H3, starts_pe, gmU_pe, H4, starts_r, gmU_r);
    head_k<<<1, 64, 0, stream>>>(gmU_pe, gmU_r, mlp_W1, mlp_b1, mlp_W2, mlp_b2, out_W, out_b, out, G);
}